// Round 4
// baseline (570.868 us; speedup 1.0000x reference)
//
#include <hip/hip_runtime.h>
#include <stdint.h>

#define N_TOK   4096
#define DMODEL  1024
#define DFF     2048
#define N_EXP   8
#define N_SLOTS (N_TOK * 2)        // 8192 (every token has exactly 2 expert slots)
#define ROWS_PAD (N_SLOTS + 128)   // padding so tile-tail OOB reads stay in-bounds
#define MT_MAX  32                 // m-tiles per expert (BM=128, worst-case cnt=4096)

typedef __bf16 bf16x8 __attribute__((ext_vector_type(8)));
typedef float  f32x4  __attribute__((ext_vector_type(4)));
typedef unsigned short u16;
typedef unsigned short u16x8 __attribute__((ext_vector_type(8)));
typedef unsigned short u16x4 __attribute__((ext_vector_type(4)));

__device__ __forceinline__ u16 f2bf(float f) {
    union { float f; uint32_t u; } v; v.f = f;
    uint32_t r = v.u + 0x7FFFu + ((v.u >> 16) & 1u);  // RTNE
    return (u16)(r >> 16);
}
__device__ __forceinline__ float bf2f(u16 u) {
    union { uint32_t u; float f; } v; v.u = ((uint32_t)u) << 16;
    return v.f;
}

// async 16B/lane global->LDS. LDS dest is wave-uniform base + lane*16 (m104 caveat).
__device__ __forceinline__ void g2l16(const void* gp, void* lp) {
    auto g = reinterpret_cast<const __attribute__((address_space(1))) unsigned int*>(
        reinterpret_cast<uintptr_t>(gp));
    auto l = reinterpret_cast<__attribute__((address_space(3))) unsigned int*>(
        reinterpret_cast<uintptr_t>(lp));
    __builtin_amdgcn_global_load_lds(g, l, 16, 0, 0);
}

// ---- XOR swizzle for 32-u16-wide LDS tiles (kept: zero cost, verified correct) ----
__device__ __forceinline__ int src_cb(int l) {
    return (l & 3) ^ ((l >> 2) & 3) ^ ((l >> 4) & 1);
}
__device__ __forceinline__ int lds_idx(int r, int cb) {
    int s = cb ^ (r & 3) ^ ((r >> 2) & 1);
    return r * 32 + s * 8;
}

// ---------------- fused weight-cvt + router (one dispatch) ----------------
#define WIN_V8  (N_EXP * 2 * DFF * DMODEL / 8)   // 4194304
#define WOUT_V8 (N_EXP * DMODEL * DFF / 8)       // 2097152
#define CVT_BLOCKS ((WIN_V8 + WOUT_V8) / 256)    // 24576
#define RTR_BLOCKS (N_TOK / 4)                   // 1024 (4 waves/block, 1 token/wave)

__global__ void cvt_router_kernel(const float4* __restrict__ win, const float4* __restrict__ wout,
                                  u16x8* __restrict__ winbf, u16x8* __restrict__ woutbf,
                                  const float* __restrict__ x, const float* __restrict__ rw,
                                  float* __restrict__ logits, int* __restrict__ tok_expert,
                                  float* __restrict__ tok_gate) {
    int bid = blockIdx.x;
    if (bid < CVT_BLOCKS) {
        int i = bid * 256 + threadIdx.x;
        const float4* s; u16x8* d; int k;
        if (i < WIN_V8) { s = win;  d = winbf;  k = i; }
        else            { s = wout; d = woutbf; k = i - WIN_V8; }
        float4 a = s[k * 2];
        float4 b = s[k * 2 + 1];
        u16x8 o = { f2bf(a.x), f2bf(a.y), f2bf(a.z), f2bf(a.w),
                    f2bf(b.x), f2bf(b.y), f2bf(b.z), f2bf(b.w) };
        d[k] = o;
        return;
    }
    // router: one wave per token, fp32 logits, exact top-2 (ties -> lowest index)
    int t = (bid - CVT_BLOCKS) * 4 + (threadIdx.x >> 6);
    int lane = threadIdx.x & 63;
    const float* xr = x + (size_t)t * DMODEL;
    float acc[N_EXP];
#pragma unroll
    for (int e = 0; e < N_EXP; ++e) acc[e] = 0.f;
    for (int i = 0; i < DMODEL / 64; ++i) {
        int k = lane + i * 64;
        float xv = xr[k];
#pragma unroll
        for (int e = 0; e < N_EXP; ++e) acc[e] += xv * rw[e * DMODEL + k];
    }
#pragma unroll
    for (int e = 0; e < N_EXP; ++e) {
        float v = acc[e];
        for (int off = 32; off > 0; off >>= 1) v += __shfl_down(v, off, 64);
        acc[e] = v;
    }
    if (lane == 0) {
        float* lg = logits + (size_t)t * N_EXP;
#pragma unroll
        for (int e = 0; e < N_EXP; ++e) lg[e] = acc[e];
        int e0 = 0; float v0 = acc[0];
#pragma unroll
        for (int e = 1; e < N_EXP; ++e) if (acc[e] > v0) { v0 = acc[e]; e0 = e; }
        int e1 = -1; float v1 = -3.0e38f;
#pragma unroll
        for (int e = 0; e < N_EXP; ++e) if (e != e0 && acc[e] > v1) { v1 = acc[e]; e1 = e; }
        float ex = expf(v1 - v0);
        tok_expert[t * 2 + 0] = e0;  tok_gate[t * 2 + 0] = 1.0f / (1.0f + ex);
        tok_expert[t * 2 + 1] = e1;  tok_gate[t * 2 + 1] = ex / (1.0f + ex);
    }
}

// ---------------- scan: count experts, prefix-sum offs, zero cursor ----------------
__global__ void scan_kernel(const int* __restrict__ tok_expert, int* __restrict__ offs,
                            int* __restrict__ cursor) {
    __shared__ int cnt[N_EXP];
    int tid = threadIdx.x;                // 256
    if (tid < N_EXP) { cnt[tid] = 0; cursor[tid] = 0; }
    __syncthreads();
    int loc[N_EXP];
#pragma unroll
    for (int e = 0; e < N_EXP; ++e) loc[e] = 0;
    for (int j = tid; j < N_SLOTS; j += 256) {
        int ex = tok_expert[j];
#pragma unroll
        for (int e = 0; e < N_EXP; ++e) loc[e] += (ex == e);
    }
#pragma unroll
    for (int e = 0; e < N_EXP; ++e) if (loc[e]) atomicAdd(&cnt[e], loc[e]);
    __syncthreads();
    if (tid == 0) {
        int s = 0;
        for (int e = 0; e < N_EXP; ++e) { offs[e] = s; s += cnt[e]; }
        offs[N_EXP] = s;
    }
}

// ---------------- gather: compact slot rows, x -> bf16, record slot->row ----------------
__global__ void gather_kernel(const float* __restrict__ x, const int* __restrict__ tok_expert,
                              const int* __restrict__ offs, int* __restrict__ cursor,
                              u16* __restrict__ Abf, int* __restrict__ inv) {
    int j = blockIdx.x;                   // slot = token*2 + s
    __shared__ int srow;
    if (threadIdx.x == 0) {
        int e = tok_expert[j];
        int pos = atomicAdd(&cursor[e], 1);
        int row = offs[e] + pos;
        inv[j] = row;
        srow = row;
    }
    __syncthreads();
    int row = srow;
    int t = j >> 1;
    float4 v = ((const float4*)(x + (size_t)t * DMODEL))[threadIdx.x];
    u16x4 o = { f2bf(v.x), f2bf(v.y), f2bf(v.z), f2bf(v.w) };
    *(u16x4*)(Abf + (size_t)row * DMODEL + threadIdx.x * 4) = o;
}

// ---------------- GEMM1: act = silu(A @ Win1^T) * (A @ Win2^T) ----------------
// BM=128 x BN=128 act-cols (256 weight rows), BK=32, 256 thr.
// Expert e pinned to XCD e via bid&7 (round-robin heuristic); per-XCD order:
// n-tile outer, m-tile inner -> weight slab (512KB x2) + A_e (~2MB) stay in that XCD's L2.
__global__ __launch_bounds__(256, 2)
void gemm1_kernel(const u16* __restrict__ Abf, const u16* __restrict__ winbf,
                  u16* __restrict__ act, const int* __restrict__ offs) {
    int bid = blockIdx.x;
    int e  = bid & 7;                     // expert == XCD
    int s  = bid >> 3;
    int nt = s >> 5;                      // 0..15 n-tile (outer)
    int mt = s & 31;                      // 0..31 m-tile (inner: weight reuse in L2)
    int cnt = offs[e + 1] - offs[e];
    if (mt * 128 >= cnt) return;
    int row0 = offs[e] + mt * 128;
    int n0 = nt * 128;
    const u16* wb = winbf + (size_t)e * (2 * DFF) * DMODEL;

    __shared__ u16 lsA[128 * 32];
    __shared__ u16 lsB[2][128 * 32];

    int tid = threadIdx.x, lane = tid & 63, wave = tid >> 6;
    int wm = wave >> 1, wn = wave & 1;

    f32x4 acc[2][4][4];
    f32x4 zero = {0.f, 0.f, 0.f, 0.f};
#pragma unroll
    for (int h = 0; h < 2; ++h)
#pragma unroll
        for (int mi = 0; mi < 4; ++mi)
#pragma unroll
            for (int ni = 0; ni < 4; ++ni) acc[h][mi][ni] = zero;

    int s_row = lane >> 2;                // 0..15 within 16-row chunk
    int s_col = src_cb(lane) * 8;         // swizzled source col-block

    for (int kk = 0; kk < DMODEL / 32; ++kk) {
        int k0 = kk * 32;
        // A tile: 128x32, 2 issues/wave
        const u16* ga = Abf + (size_t)(row0 + wave * 32 + s_row) * DMODEL + k0 + s_col;
        g2l16(ga, &lsA[(wave * 32) * 32]);
        g2l16(ga + 16 * DMODEL, &lsA[(wave * 32 + 16) * 32]);
        // B tiles: h1 rows [n0,n0+128), h2 rows [DFF+n0, DFF+n0+128): 2 issues/wave each
#pragma unroll
        for (int h = 0; h < 2; ++h) {
            const u16* gb = wb + (size_t)(h * DFF + n0 + wave * 32 + s_row) * DMODEL + k0 + s_col;
            g2l16(gb, &lsB[h][(wave * 32) * 32]);
            g2l16(gb + 16 * DMODEL, &lsB[h][(wave * 32 + 16) * 32]);
        }
        __syncthreads();
        bf16x8 afr[4];
#pragma unroll
        for (int mi = 0; mi < 4; ++mi)
            afr[mi] = *(const bf16x8*)&lsA[lds_idx(wm * 64 + mi * 16 + (lane & 15), lane >> 4)];
#pragma unroll
        for (int h = 0; h < 2; ++h)
#pragma unroll
            for (int ni = 0; ni < 4; ++ni) {
                bf16x8 bfr = *(const bf16x8*)&lsB[h][lds_idx(wn * 64 + ni * 16 + (lane & 15), lane >> 4)];
#pragma unroll
                for (int mi = 0; mi < 4; ++mi)
                    acc[h][mi][ni] = __builtin_amdgcn_mfma_f32_16x16x32_bf16(
                        afr[mi], bfr, acc[h][mi][ni], 0, 0, 0);
            }
        __syncthreads();
    }
    // epilogue: act = silu(h1) * h2, store bf16
    int mmax = cnt - mt * 128;
#pragma unroll
    for (int mi = 0; mi < 4; ++mi)
#pragma unroll
        for (int i = 0; i < 4; ++i) {
            int rl = wm * 64 + mi * 16 + (lane >> 4) * 4 + i;
            if (rl < mmax) {
                size_t rp = (size_t)(row0 + rl) * DFF;
#pragma unroll
                for (int ni = 0; ni < 4; ++ni) {
                    int col = n0 + wn * 64 + ni * 16 + (lane & 15);
                    float a = acc[0][mi][ni][i];
                    float b = acc[1][mi][ni][i];
                    float sv = a / (1.0f + __expf(-a));
                    act[rp + col] = f2bf(sv * b);
                }
            }
        }
}

// ---------------- GEMM2: y = act @ Wout^T, split-K=2, expert->XCD, bf16 stores ----------------
// BM=128 x BN=128, BK=32, K=1024/block
__global__ __launch_bounds__(256, 2)
void gemm2_kernel(const u16* __restrict__ act, const u16* __restrict__ woutbf,
                  u16* __restrict__ ybA, u16* __restrict__ ybB,
                  const int* __restrict__ offs) {
    int bid = blockIdx.x;
    int e  = bid & 7;                     // expert == XCD
    int s  = bid >> 3;                    // kc(2) x nt(8) x mt(32)
    int kc = s >> 8;
    int nt = (s >> 5) & 7;
    int mt = s & 31;
    int cnt = offs[e + 1] - offs[e];
    if (mt * 128 >= cnt) return;
    int row0 = offs[e] + mt * 128;
    int n0 = nt * 128;
    const u16* wb = woutbf + (size_t)e * DMODEL * DFF;

    __shared__ u16 lsA[128 * 32];
    __shared__ u16 lsB[128 * 32];

    int tid = threadIdx.x, lane = tid & 63, wave = tid >> 6;
    int wm = wave >> 1, wn = wave & 1;

    f32x4 acc[4][4];
    f32x4 zero = {0.f, 0.f, 0.f, 0.f};
#pragma unroll
    for (int mi = 0; mi < 4; ++mi)
#pragma unroll
        for (int ni = 0; ni < 4; ++ni) acc[mi][ni] = zero;

    int s_row = lane >> 2;
    int s_col = src_cb(lane) * 8;

    for (int kk = kc * 32; kk < kc * 32 + 32; ++kk) {
        int k0 = kk * 32;
        const u16* ga = act + (size_t)(row0 + wave * 32 + s_row) * DFF + k0 + s_col;
        g2l16(ga, &lsA[(wave * 32) * 32]);
        g2l16(ga + 16 * DFF, &lsA[(wave * 32 + 16) * 32]);
        const u16* gb = wb + (size_t)(n0 + wave * 32 + s_row) * DFF + k0 + s_col;
        g2l16(gb, &lsB[(wave * 32) * 32]);
        g2l16(gb + 16 * DFF, &lsB[(wave * 32 + 16) * 32]);
        __syncthreads();
        bf16x8 afr[4];
#pragma unroll
        for (int mi = 0; mi < 4; ++mi)
            afr[mi] = *(const bf16x8*)&lsA[lds_idx(wm * 64 + mi * 16 + (lane & 15), lane >> 4)];
#pragma unroll
        for (int ni = 0; ni < 4; ++ni) {
            bf16x8 bfr = *(const bf16x8*)&lsB[lds_idx(wn * 64 + ni * 16 + (lane & 15), lane >> 4)];
#pragma unroll
            for (int mi = 0; mi < 4; ++mi)
                acc[mi][ni] = __builtin_amdgcn_mfma_f32_16x16x32_bf16(
                    afr[mi], bfr, acc[mi][ni], 0, 0, 0);
        }
        __syncthreads();
    }
    u16* yb = kc ? ybB : ybA;
    int mmax = cnt - mt * 128;
#pragma unroll
    for (int mi = 0; mi < 4; ++mi)
#pragma unroll
        for (int i = 0; i < 4; ++i) {
            int rl = wm * 64 + mi * 16 + (lane >> 4) * 4 + i;
            if (rl < mmax) {
                u16* yrow = yb + (size_t)(row0 + rl) * DMODEL;
#pragma unroll
                for (int ni = 0; ni < 4; ++ni) {
                    int col = n0 + wn * 64 + ni * 16 + (lane & 15);
                    yrow[col] = f2bf(acc[mi][ni][i]);
                }
            }
        }
}

// ---------------- combine: out[t] = g0*(y0a+y0b) + g1*(y1a+y1b) ----------------
__global__ void combine_kernel(const u16* __restrict__ ybA, const u16* __restrict__ ybB,
                               const int* __restrict__ inv, const float* __restrict__ tok_gate,
                               float* __restrict__ out) {
    int t = blockIdx.x;
    int tid = threadIdx.x;                // 256
    __shared__ int sr0, sr1;
    __shared__ float sg0, sg1;
    if (tid == 0) {
        sr0 = inv[t * 2];  sr1 = inv[t * 2 + 1];
        sg0 = tok_gate[t * 2];  sg1 = tok_gate[t * 2 + 1];
    }
    __syncthreads();
    int d = tid * 4;
    u16x4 a0 = *(const u16x4*)(ybA + (size_t)sr0 * DMODEL + d);
    u16x4 b0 = *(const u16x4*)(ybB + (size_t)sr0 * DMODEL + d);
    u16x4 a1 = *(const u16x4*)(ybA + (size_t)sr1 * DMODEL + d);
    u16x4 b1 = *(const u16x4*)(ybB + (size_t)sr1 * DMODEL + d);
    float4 o;
    o.x = sg0 * (bf2f(a0.x) + bf2f(b0.x)) + sg1 * (bf2f(a1.x) + bf2f(b1.x));
    o.y = sg0 * (bf2f(a0.y) + bf2f(b0.y)) + sg1 * (bf2f(a1.y) + bf2f(b1.y));
    o.z = sg0 * (bf2f(a0.z) + bf2f(b0.z)) + sg1 * (bf2f(a1.z) + bf2f(b1.z));
    o.w = sg0 * (bf2f(a0.w) + bf2f(b0.w)) + sg1 * (bf2f(a1.w) + bf2f(b1.w));
    *(float4*)(out + (size_t)t * DMODEL + d) = o;
}

// ---------------- launch ----------------
extern "C" void kernel_launch(void* const* d_in, const int* in_sizes, int n_in,
                              void* d_out, int out_size, void* d_ws, size_t ws_size,
                              hipStream_t stream) {
    const float* x    = (const float*)d_in[0];   // [4096, 1024]
    const float* rw   = (const float*)d_in[1];   // [8, 1024]
    const float* win  = (const float*)d_in[2];   // [8, 4096, 1024]
    const float* wout = (const float*)d_in[3];   // [8, 1024, 2048]
    float* out    = (float*)d_out;               // [4096, 1024]
    float* logits = out + (size_t)N_TOK * DMODEL; // [4096, 8]

    char* ws = (char*)d_ws;
    size_t o = 0;
    auto alloc = [&](size_t bytes) -> void* {
        void* p = ws + o;
        o = (o + bytes + 255) & ~(size_t)255;
        return p;
    };
    u16*   Abf      = (u16*)  alloc((size_t)ROWS_PAD * DMODEL * 2);        // 17.0 MB
    u16*   actbuf   = (u16*)  alloc((size_t)ROWS_PAD * DFF * 2);           // 34.1 MB
    u16*   winbf    = (u16*)  alloc((size_t)N_EXP * 2 * DFF * DMODEL * 2); // 67.1 MB
    u16*   woutbf   = (u16*)  alloc((size_t)N_EXP * DMODEL * DFF * 2);     // 33.6 MB
    int*   offs     = (int*)  alloc(16 * 4);
    int*   cursor   = (int*)  alloc(N_EXP * 4);
    int*   inv      = (int*)  alloc(N_SLOTS * 4);
    int*   tok_exp  = (int*)  alloc(N_SLOTS * 4);
    float* tok_gate = (float*)alloc(N_SLOTS * 4);
    // ybA/ybB alias winbf: winbf (67.1 MB) is dead after gemm1, yb needs 2x17 MB
    u16*   ybA      = winbf;
    u16*   ybB      = winbf + (size_t)ROWS_PAD * DMODEL;
    (void)ws_size; (void)in_sizes; (void)n_in; (void)out_size;

    cvt_router_kernel<<<CVT_BLOCKS + RTR_BLOCKS, 256, 0, stream>>>(
        (const float4*)win, (const float4*)wout, (u16x8*)winbf, (u16x8*)woutbf,
        x, rw, logits, tok_exp, tok_gate);
    scan_kernel<<<1, 256, 0, stream>>>(tok_exp, offs, cursor);
    gather_kernel<<<N_SLOTS, 256, 0, stream>>>(x, tok_exp, offs, cursor, Abf, inv);
    gemm1_kernel<<<8 * 16 * MT_MAX, 256, 0, stream>>>(Abf, winbf, actbuf, offs);
    gemm2_kernel<<<8 * 2 * 8 * MT_MAX, 256, 0, stream>>>(actbuf, woutbf, ybA, ybB, offs);
    combine_kernel<<<N_TOK, 256, 0, stream>>>(ybA, ybB, inv, tok_gate, out);
}

// Round 5
// 559.551 us; speedup vs baseline: 1.0202x; 1.0202x over previous
//
#include <hip/hip_runtime.h>
#include <stdint.h>

#define N_TOK   4096
#define DMODEL  1024
#define DFF     2048
#define N_EXP   8
#define N_SLOTS (N_TOK * 2)        // 8192 (every token has exactly 2 expert slots)
#define ROWS_PAD (N_SLOTS + 128)   // padding so tile-tail OOB reads stay in-bounds
#define MT_MAX  32                 // m-tiles per expert (BM=128)

typedef __bf16 bf16x8 __attribute__((ext_vector_type(8)));
typedef float  f32x4  __attribute__((ext_vector_type(4)));
typedef unsigned short u16;
typedef unsigned short u16x8 __attribute__((ext_vector_type(8)));
typedef unsigned short u16x4 __attribute__((ext_vector_type(4)));

__device__ __forceinline__ u16 f2bf(float f) {
    union { float f; uint32_t u; } v; v.f = f;
    uint32_t r = v.u + 0x7FFFu + ((v.u >> 16) & 1u);  // RTNE
    return (u16)(r >> 16);
}
__device__ __forceinline__ float bf2f(u16 u) {
    union { uint32_t u; float f; } v; v.u = ((uint32_t)u) << 16;
    return v.f;
}

// async 16B/lane global->LDS. LDS dest is wave-uniform base + lane*16 (m104 caveat).
__device__ __forceinline__ void g2l16(const void* gp, void* lp) {
    auto g = reinterpret_cast<const __attribute__((address_space(1))) unsigned int*>(
        reinterpret_cast<uintptr_t>(gp));
    auto l = reinterpret_cast<__attribute__((address_space(3))) unsigned int*>(
        reinterpret_cast<uintptr_t>(lp));
    __builtin_amdgcn_global_load_lds(g, l, 16, 0, 0);
}

// ---- XOR swizzle for 32-u16-wide LDS tiles ----
__device__ __forceinline__ int src_cb(int l) {
    return (l & 3) ^ ((l >> 2) & 3) ^ ((l >> 4) & 1);
}
__device__ __forceinline__ int lds_idx(int r, int cb) {
    int s = cb ^ (r & 3) ^ ((r >> 2) & 1);
    return r * 32 + s * 8;
}

// ---------------- fused weight-cvt + router (one dispatch) ----------------
#define WIN_V8  (N_EXP * 2 * DFF * DMODEL / 8)   // 4194304
#define WOUT_V8 (N_EXP * DMODEL * DFF / 8)       // 2097152
#define CVT_BLOCKS ((WIN_V8 + WOUT_V8) / 256)    // 24576
#define RTR_BLOCKS (N_TOK / 4)                   // 1024 (4 waves/block, 1 token/wave)

__global__ void cvt_router_kernel(const float4* __restrict__ win, const float4* __restrict__ wout,
                                  u16x8* __restrict__ winbf, u16x8* __restrict__ woutbf,
                                  const float* __restrict__ x, const float* __restrict__ rw,
                                  float* __restrict__ logits, int* __restrict__ tok_expert,
                                  float* __restrict__ tok_gate) {
    int bid = blockIdx.x;
    if (bid < CVT_BLOCKS) {
        int i = bid * 256 + threadIdx.x;
        const float4* s; u16x8* d; int k;
        if (i < WIN_V8) { s = win;  d = winbf;  k = i; }
        else            { s = wout; d = woutbf; k = i - WIN_V8; }
        float4 a = s[k * 2];
        float4 b = s[k * 2 + 1];
        u16x8 o = { f2bf(a.x), f2bf(a.y), f2bf(a.z), f2bf(a.w),
                    f2bf(b.x), f2bf(b.y), f2bf(b.z), f2bf(b.w) };
        d[k] = o;
        return;
    }
    // router: one wave per token, fp32 logits, exact top-2 (ties -> lowest index)
    int t = (bid - CVT_BLOCKS) * 4 + (threadIdx.x >> 6);
    int lane = threadIdx.x & 63;
    const float* xr = x + (size_t)t * DMODEL;
    float acc[N_EXP];
#pragma unroll
    for (int e = 0; e < N_EXP; ++e) acc[e] = 0.f;
    for (int i = 0; i < DMODEL / 64; ++i) {
        int k = lane + i * 64;
        float xv = xr[k];
#pragma unroll
        for (int e = 0; e < N_EXP; ++e) acc[e] += xv * rw[e * DMODEL + k];
    }
#pragma unroll
    for (int e = 0; e < N_EXP; ++e) {
        float v = acc[e];
        for (int off = 32; off > 0; off >>= 1) v += __shfl_down(v, off, 64);
        acc[e] = v;
    }
    if (lane == 0) {
        float* lg = logits + (size_t)t * N_EXP;
#pragma unroll
        for (int e = 0; e < N_EXP; ++e) lg[e] = acc[e];
        int e0 = 0; float v0 = acc[0];
#pragma unroll
        for (int e = 1; e < N_EXP; ++e) if (acc[e] > v0) { v0 = acc[e]; e0 = e; }
        int e1 = -1; float v1 = -3.0e38f;
#pragma unroll
        for (int e = 0; e < N_EXP; ++e) if (e != e0 && acc[e] > v1) { v1 = acc[e]; e1 = e; }
        float ex = expf(v1 - v0);
        tok_expert[t * 2 + 0] = e0;  tok_gate[t * 2 + 0] = 1.0f / (1.0f + ex);
        tok_expert[t * 2 + 1] = e1;  tok_gate[t * 2 + 1] = ex / (1.0f + ex);
    }
}

// ---------------- scan: count experts, prefix-sum offs, zero cursor ----------------
__global__ void scan_kernel(const int* __restrict__ tok_expert, int* __restrict__ offs,
                            int* __restrict__ cursor) {
    __shared__ int cnt[N_EXP];
    int tid = threadIdx.x;                // 256
    if (tid < N_EXP) { cnt[tid] = 0; cursor[tid] = 0; }
    __syncthreads();
    int loc[N_EXP];
#pragma unroll
    for (int e = 0; e < N_EXP; ++e) loc[e] = 0;
    for (int j = tid; j < N_SLOTS; j += 256) {
        int ex = tok_expert[j];
#pragma unroll
        for (int e = 0; e < N_EXP; ++e) loc[e] += (ex == e);
    }
#pragma unroll
    for (int e = 0; e < N_EXP; ++e) if (loc[e]) atomicAdd(&cnt[e], loc[e]);
    __syncthreads();
    if (tid == 0) {
        int s = 0;
        for (int e = 0; e < N_EXP; ++e) { offs[e] = s; s += cnt[e]; }
        offs[N_EXP] = s;
    }
}

// ---------------- gather: compact slot rows, x -> bf16, record slot->row ----------------
__global__ void gather_kernel(const float* __restrict__ x, const int* __restrict__ tok_expert,
                              const int* __restrict__ offs, int* __restrict__ cursor,
                              u16* __restrict__ Abf, int* __restrict__ inv) {
    int j = blockIdx.x;                   // slot = token*2 + s
    __shared__ int srow;
    if (threadIdx.x == 0) {
        int e = tok_expert[j];
        int pos = atomicAdd(&cursor[e], 1);
        int row = offs[e] + pos;
        inv[j] = row;
        srow = row;
    }
    __syncthreads();
    int row = srow;
    int t = j >> 1;
    float4 v = ((const float4*)(x + (size_t)t * DMODEL))[threadIdx.x];
    u16x4 o = { f2bf(v.x), f2bf(v.y), f2bf(v.z), f2bf(v.w) };
    *(u16x4*)(Abf + (size_t)row * DMODEL + threadIdx.x * 4) = o;
}

// ---------------- GEMM1: act = silu(A @ Win1^T) * (A @ Win2^T) ----------------
// BM=128 x BN=64 act-cols (x2 SwiGLU halves), BK=32. Expert e pinned to XCD e
// (bid&7); nt outer / mt inner so the (e,nt) weight slab + A_e stay in that XCD's L2.
// launch_bounds(256,4): 56 VGPR + 64 AGPR = 120 <= 128 regs -> 4 blocks/CU.
__global__ __launch_bounds__(256, 4)
void gemm1_kernel(const u16* __restrict__ Abf, const u16* __restrict__ winbf,
                  u16* __restrict__ act, const int* __restrict__ offs) {
    int bid = blockIdx.x;
    int e  = bid & 7;                     // expert == XCD (blockIdx % 8 heuristic)
    int s  = bid >> 3;
    int mt = s & 31;                      // m-tile (inner: weight slab reused in L2)
    int nt = s >> 5;                      // 0..31 n-tile (outer)
    int cnt = offs[e + 1] - offs[e];
    if (mt * 128 >= cnt) return;
    int row0 = offs[e] + mt * 128;
    int n0 = nt * 64;
    const u16* wb = winbf + (size_t)e * (2 * DFF) * DMODEL;

    __shared__ u16 lsA[128 * 32];
    __shared__ u16 lsB[2][64 * 32];

    int tid = threadIdx.x, lane = tid & 63, wave = tid >> 6;
    int wm = wave >> 1, wn = wave & 1;

    f32x4 acc[2][4][2];
    f32x4 zero = {0.f, 0.f, 0.f, 0.f};
#pragma unroll
    for (int h = 0; h < 2; ++h)
#pragma unroll
        for (int mi = 0; mi < 4; ++mi)
#pragma unroll
            for (int ni = 0; ni < 2; ++ni) acc[h][mi][ni] = zero;

    int s_row = lane >> 2;                // 0..15 within 16-row chunk
    int s_col = src_cb(lane) * 8;         // swizzled source col-block

    for (int kk = 0; kk < DMODEL / 32; ++kk) {
        int k0 = kk * 32;
        // A tile: 128x32 bf16, 2 async issues/wave (16 rows each)
        const u16* ga = Abf + (size_t)(row0 + wave * 32 + s_row) * DMODEL + k0 + s_col;
        g2l16(ga, &lsA[(wave * 32) * 32]);
        g2l16(ga + 16 * DMODEL, &lsA[(wave * 32 + 16) * 32]);
        // B tiles (h1 rows n0.., h2 rows n0+DFF..): 1 async issue/wave per half
        const u16* gb0 = wb + (size_t)(n0 + wave * 16 + s_row) * DMODEL + k0 + s_col;
        g2l16(gb0, &lsB[0][(wave * 16) * 32]);
        g2l16(gb0 + (size_t)DFF * DMODEL, &lsB[1][(wave * 16) * 32]);
        __syncthreads();
        bf16x8 afr[4];
#pragma unroll
        for (int mi = 0; mi < 4; ++mi)
            afr[mi] = *(const bf16x8*)&lsA[lds_idx(wm * 64 + mi * 16 + (lane & 15), lane >> 4)];
#pragma unroll
        for (int h = 0; h < 2; ++h)
#pragma unroll
            for (int ni = 0; ni < 2; ++ni) {
                bf16x8 bfr = *(const bf16x8*)&lsB[h][lds_idx(wn * 32 + ni * 16 + (lane & 15), lane >> 4)];
#pragma unroll
                for (int mi = 0; mi < 4; ++mi)
                    acc[h][mi][ni] = __builtin_amdgcn_mfma_f32_16x16x32_bf16(
                        afr[mi], bfr, acc[h][mi][ni], 0, 0, 0);
            }
        __syncthreads();
    }
    // epilogue: act = silu(h1) * h2, store bf16
    int mmax = cnt - mt * 128;
#pragma unroll
    for (int mi = 0; mi < 4; ++mi)
#pragma unroll
        for (int i = 0; i < 4; ++i) {
            int rl = wm * 64 + mi * 16 + (lane >> 4) * 4 + i;
            if (rl < mmax) {
                size_t rp = (size_t)(row0 + rl) * DFF;
#pragma unroll
                for (int ni = 0; ni < 2; ++ni) {
                    int col = n0 + wn * 32 + ni * 16 + (lane & 15);
                    float a = acc[0][mi][ni][i];
                    float b = acc[1][mi][ni][i];
                    float sv = a / (1.0f + __expf(-a));
                    act[rp + col] = f2bf(sv * b);
                }
            }
        }
}

// ---------------- GEMM2: y = act @ Wout^T, split-K=2, expert->XCD, bf16 stores ----------------
// BM=128 x BN=128, BK=32, K=1024/block
__global__ __launch_bounds__(256, 4)
void gemm2_kernel(const u16* __restrict__ act, const u16* __restrict__ woutbf,
                  u16* __restrict__ ybA, u16* __restrict__ ybB,
                  const int* __restrict__ offs) {
    int bid = blockIdx.x;
    int e  = bid & 7;                     // expert == XCD
    int s  = bid >> 3;                    // kc(2) x nt(8) x mt(32), mt inner
    int mt = s & 31;
    int nt = (s >> 5) & 7;
    int kc = s >> 8;
    int cnt = offs[e + 1] - offs[e];
    if (mt * 128 >= cnt) return;
    int row0 = offs[e] + mt * 128;
    int n0 = nt * 128;
    const u16* wb = woutbf + (size_t)e * DMODEL * DFF;

    __shared__ u16 lsA[128 * 32];
    __shared__ u16 lsB[128 * 32];

    int tid = threadIdx.x, lane = tid & 63, wave = tid >> 6;
    int wm = wave >> 1, wn = wave & 1;

    f32x4 acc[4][4];
    f32x4 zero = {0.f, 0.f, 0.f, 0.f};
#pragma unroll
    for (int mi = 0; mi < 4; ++mi)
#pragma unroll
        for (int ni = 0; ni < 4; ++ni) acc[mi][ni] = zero;

    int s_row = lane >> 2;
    int s_col = src_cb(lane) * 8;

    for (int kk = kc * 32; kk < kc * 32 + 32; ++kk) {
        int k0 = kk * 32;
        const u16* ga = act + (size_t)(row0 + wave * 32 + s_row) * DFF + k0 + s_col;
        g2l16(ga, &lsA[(wave * 32) * 32]);
        g2l16(ga + 16 * DFF, &lsA[(wave * 32 + 16) * 32]);
        const u16* gb = wb + (size_t)(n0 + wave * 32 + s_row) * DFF + k0 + s_col;
        g2l16(gb, &lsB[(wave * 32) * 32]);
        g2l16(gb + 16 * DFF, &lsB[(wave * 32 + 16) * 32]);
        __syncthreads();
        bf16x8 afr[4];
#pragma unroll
        for (int mi = 0; mi < 4; ++mi)
            afr[mi] = *(const bf16x8*)&lsA[lds_idx(wm * 64 + mi * 16 + (lane & 15), lane >> 4)];
#pragma unroll
        for (int ni = 0; ni < 4; ++ni) {
            bf16x8 bfr = *(const bf16x8*)&lsB[lds_idx(wn * 64 + ni * 16 + (lane & 15), lane >> 4)];
#pragma unroll
            for (int mi = 0; mi < 4; ++mi)
                acc[mi][ni] = __builtin_amdgcn_mfma_f32_16x16x32_bf16(
                    afr[mi], bfr, acc[mi][ni], 0, 0, 0);
        }
        __syncthreads();
    }
    u16* yb = kc ? ybB : ybA;
    int mmax = cnt - mt * 128;
#pragma unroll
    for (int mi = 0; mi < 4; ++mi)
#pragma unroll
        for (int i = 0; i < 4; ++i) {
            int rl = wm * 64 + mi * 16 + (lane >> 4) * 4 + i;
            if (rl < mmax) {
                u16* yrow = yb + (size_t)(row0 + rl) * DMODEL;
#pragma unroll
                for (int ni = 0; ni < 4; ++ni) {
                    int col = n0 + wn * 64 + ni * 16 + (lane & 15);
                    yrow[col] = f2bf(acc[mi][ni][i]);
                }
            }
        }
}

// ---------------- combine: out[t] = g0*(y0a+y0b) + g1*(y1a+y1b) ----------------
__global__ void combine_kernel(const u16* __restrict__ ybA, const u16* __restrict__ ybB,
                               const int* __restrict__ inv, const float* __restrict__ tok_gate,
                               float* __restrict__ out) {
    int t = blockIdx.x;
    int tid = threadIdx.x;                // 256
    __shared__ int sr0, sr1;
    __shared__ float sg0, sg1;
    if (tid == 0) {
        sr0 = inv[t * 2];  sr1 = inv[t * 2 + 1];
        sg0 = tok_gate[t * 2];  sg1 = tok_gate[t * 2 + 1];
    }
    __syncthreads();
    int d = tid * 4;
    u16x4 a0 = *(const u16x4*)(ybA + (size_t)sr0 * DMODEL + d);
    u16x4 b0 = *(const u16x4*)(ybB + (size_t)sr0 * DMODEL + d);
    u16x4 a1 = *(const u16x4*)(ybA + (size_t)sr1 * DMODEL + d);
    u16x4 b1 = *(const u16x4*)(ybB + (size_t)sr1 * DMODEL + d);
    float4 o;
    o.x = sg0 * (bf2f(a0.x) + bf2f(b0.x)) + sg1 * (bf2f(a1.x) + bf2f(b1.x));
    o.y = sg0 * (bf2f(a0.y) + bf2f(b0.y)) + sg1 * (bf2f(a1.y) + bf2f(b1.y));
    o.z = sg0 * (bf2f(a0.z) + bf2f(b0.z)) + sg1 * (bf2f(a1.z) + bf2f(b1.z));
    o.w = sg0 * (bf2f(a0.w) + bf2f(b0.w)) + sg1 * (bf2f(a1.w) + bf2f(b1.w));
    *(float4*)(out + (size_t)t * DMODEL + d) = o;
}

// ---------------- launch ----------------
extern "C" void kernel_launch(void* const* d_in, const int* in_sizes, int n_in,
                              void* d_out, int out_size, void* d_ws, size_t ws_size,
                              hipStream_t stream) {
    const float* x    = (const float*)d_in[0];   // [4096, 1024]
    const float* rw   = (const float*)d_in[1];   // [8, 1024]
    const float* win  = (const float*)d_in[2];   // [8, 4096, 1024]
    const float* wout = (const float*)d_in[3];   // [8, 1024, 2048]
    float* out    = (float*)d_out;               // [4096, 1024]
    float* logits = out + (size_t)N_TOK * DMODEL; // [4096, 8]

    char* ws = (char*)d_ws;
    size_t o = 0;
    auto alloc = [&](size_t bytes) -> void* {
        void* p = ws + o;
        o = (o + bytes + 255) & ~(size_t)255;
        return p;
    };
    u16*   Abf      = (u16*)  alloc((size_t)ROWS_PAD * DMODEL * 2);        // 17.0 MB
    u16*   actbuf   = (u16*)  alloc((size_t)ROWS_PAD * DFF * 2);           // 34.1 MB
    u16*   winbf    = (u16*)  alloc((size_t)N_EXP * 2 * DFF * DMODEL * 2); // 67.1 MB
    u16*   woutbf   = (u16*)  alloc((size_t)N_EXP * DMODEL * DFF * 2);     // 33.6 MB
    int*   offs     = (int*)  alloc(16 * 4);
    int*   cursor   = (int*)  alloc(N_EXP * 4);
    int*   inv      = (int*)  alloc(N_SLOTS * 4);
    int*   tok_exp  = (int*)  alloc(N_SLOTS * 4);
    float* tok_gate = (float*)alloc(N_SLOTS * 4);
    // ybA/ybB alias winbf: winbf is dead after gemm1, yb needs 2x17 MB
    u16*   ybA      = winbf;
    u16*   ybB      = winbf + (size_t)ROWS_PAD * DMODEL;
    (void)ws_size; (void)in_sizes; (void)n_in; (void)out_size;

    cvt_router_kernel<<<CVT_BLOCKS + RTR_BLOCKS, 256, 0, stream>>>(
        (const float4*)win, (const float4*)wout, (u16x8*)winbf, (u16x8*)woutbf,
        x, rw, logits, tok_exp, tok_gate);
    scan_kernel<<<1, 256, 0, stream>>>(tok_exp, offs, cursor);
    gather_kernel<<<N_SLOTS, 256, 0, stream>>>(x, tok_exp, offs, cursor, Abf, inv);
    gemm1_kernel<<<8 * 32 * MT_MAX, 256, 0, stream>>>(Abf, winbf, actbuf, offs);
    gemm2_kernel<<<8 * 2 * 8 * MT_MAX, 256, 0, stream>>>(actbuf, woutbf, ybA, ybB, offs);
    combine_kernel<<<N_TOK, 256, 0, stream>>>(ybA, ybB, inv, tok_gate, out);
}

// Round 6
// 552.350 us; speedup vs baseline: 1.0335x; 1.0130x over previous
//
#include <hip/hip_runtime.h>
#include <stdint.h>

#define N_TOK   4096
#define DMODEL  1024
#define DFF     2048
#define N_EXP   8
#define N_SLOTS (N_TOK * 2)        // 8192 (every token has exactly 2 expert slots)
#define ROWS_PAD (N_SLOTS + 128)   // padding so tile-tail OOB reads stay in-bounds

typedef __bf16 bf16x8 __attribute__((ext_vector_type(8)));
typedef float  f32x4  __attribute__((ext_vector_type(4)));
typedef unsigned short u16;
typedef unsigned short u16x8 __attribute__((ext_vector_type(8)));
typedef unsigned short u16x4 __attribute__((ext_vector_type(4)));

__device__ __forceinline__ u16 f2bf(float f) {
    union { float f; uint32_t u; } v; v.f = f;
    uint32_t r = v.u + 0x7FFFu + ((v.u >> 16) & 1u);  // RTNE
    return (u16)(r >> 16);
}
__device__ __forceinline__ float bf2f(u16 u) {
    union { uint32_t u; float f; } v; v.u = ((uint32_t)u) << 16;
    return v.f;
}

// async 16B/lane global->LDS. LDS dest is wave-uniform base + lane*16 (m104 caveat).
__device__ __forceinline__ void g2l16(const void* gp, void* lp) {
    auto g = reinterpret_cast<const __attribute__((address_space(1))) unsigned int*>(
        reinterpret_cast<uintptr_t>(gp));
    auto l = reinterpret_cast<__attribute__((address_space(3))) unsigned int*>(
        reinterpret_cast<uintptr_t>(lp));
    __builtin_amdgcn_global_load_lds(g, l, 16, 0, 0);
}

// ---- XOR swizzle for 64-u16-wide (128B-row) LDS tiles: 8 col-blocks of 16B ----
// slot(r,cb) = cb ^ (r&7). Frag reads land 2 lanes/bank (free, m136).
// g2l16 loader covers 8 rows/issue; lane l -> row R0+(l>>3), slot l&7, so the
// global col-block it must fetch is (l&7)^(l>>3) (R0 is 8-row aligned).
__device__ __forceinline__ int idx64(int r, int cb) {
    return r * 64 + ((cb ^ (r & 7)) * 8);
}

// ---------------- fused weight-cvt + router (one dispatch) ----------------
#define WIN_V8  (N_EXP * 2 * DFF * DMODEL / 8)   // 4194304
#define WOUT_V8 (N_EXP * DMODEL * DFF / 8)       // 2097152
#define CVT_BLOCKS ((WIN_V8 + WOUT_V8) / 256)    // 24576
#define RTR_BLOCKS (N_TOK / 4)                   // 1024 (4 waves/block, 1 token/wave)

__global__ void cvt_router_kernel(const float4* __restrict__ win, const float4* __restrict__ wout,
                                  u16x8* __restrict__ winbf, u16x8* __restrict__ woutbf,
                                  const float* __restrict__ x, const float* __restrict__ rw,
                                  float* __restrict__ logits, int* __restrict__ tok_expert,
                                  float* __restrict__ tok_gate) {
    int bid = blockIdx.x;
    if (bid < CVT_BLOCKS) {
        int i = bid * 256 + threadIdx.x;
        const float4* s; u16x8* d; int k;
        if (i < WIN_V8) { s = win;  d = winbf;  k = i; }
        else            { s = wout; d = woutbf; k = i - WIN_V8; }
        float4 a = s[k * 2];
        float4 b = s[k * 2 + 1];
        u16x8 o = { f2bf(a.x), f2bf(a.y), f2bf(a.z), f2bf(a.w),
                    f2bf(b.x), f2bf(b.y), f2bf(b.z), f2bf(b.w) };
        d[k] = o;
        return;
    }
    // router: one wave per token, fp32 logits, exact top-2 (ties -> lowest index)
    int t = (bid - CVT_BLOCKS) * 4 + (threadIdx.x >> 6);
    int lane = threadIdx.x & 63;
    const float* xr = x + (size_t)t * DMODEL;
    float acc[N_EXP];
#pragma unroll
    for (int e = 0; e < N_EXP; ++e) acc[e] = 0.f;
    for (int i = 0; i < DMODEL / 64; ++i) {
        int k = lane + i * 64;
        float xv = xr[k];
#pragma unroll
        for (int e = 0; e < N_EXP; ++e) acc[e] += xv * rw[e * DMODEL + k];
    }
#pragma unroll
    for (int e = 0; e < N_EXP; ++e) {
        float v = acc[e];
        for (int off = 32; off > 0; off >>= 1) v += __shfl_down(v, off, 64);
        acc[e] = v;
    }
    if (lane == 0) {
        float* lg = logits + (size_t)t * N_EXP;
#pragma unroll
        for (int e = 0; e < N_EXP; ++e) lg[e] = acc[e];
        int e0 = 0; float v0 = acc[0];
#pragma unroll
        for (int e = 1; e < N_EXP; ++e) if (acc[e] > v0) { v0 = acc[e]; e0 = e; }
        int e1 = -1; float v1 = -3.0e38f;
#pragma unroll
        for (int e = 0; e < N_EXP; ++e) if (e != e0 && acc[e] > v1) { v1 = acc[e]; e1 = e; }
        float ex = expf(v1 - v0);
        tok_expert[t * 2 + 0] = e0;  tok_gate[t * 2 + 0] = 1.0f / (1.0f + ex);
        tok_expert[t * 2 + 1] = e1;  tok_gate[t * 2 + 1] = ex / (1.0f + ex);
    }
}

// ---------------- scan: count experts, prefix-sum offs, zero cursor ----------------
__global__ void scan_kernel(const int* __restrict__ tok_expert, int* __restrict__ offs,
                            int* __restrict__ cursor) {
    __shared__ int cnt[N_EXP];
    int tid = threadIdx.x;                // 256
    if (tid < N_EXP) { cnt[tid] = 0; cursor[tid] = 0; }
    __syncthreads();
    int loc[N_EXP];
#pragma unroll
    for (int e = 0; e < N_EXP; ++e) loc[e] = 0;
    for (int j = tid; j < N_SLOTS; j += 256) {
        int ex = tok_expert[j];
#pragma unroll
        for (int e = 0; e < N_EXP; ++e) loc[e] += (ex == e);
    }
#pragma unroll
    for (int e = 0; e < N_EXP; ++e) if (loc[e]) atomicAdd(&cnt[e], loc[e]);
    __syncthreads();
    if (tid == 0) {
        int s = 0;
        for (int e = 0; e < N_EXP; ++e) { offs[e] = s; s += cnt[e]; }
        offs[N_EXP] = s;
    }
}

// ---------------- gather: compact slot rows, x -> bf16, record slot->row ----------------
__global__ void gather_kernel(const float* __restrict__ x, const int* __restrict__ tok_expert,
                              const int* __restrict__ offs, int* __restrict__ cursor,
                              u16* __restrict__ Abf, int* __restrict__ inv) {
    int j = blockIdx.x;                   // slot = token*2 + s
    __shared__ int srow;
    if (threadIdx.x == 0) {
        int e = tok_expert[j];
        int pos = atomicAdd(&cursor[e], 1);
        int row = offs[e] + pos;
        inv[j] = row;
        srow = row;
    }
    __syncthreads();
    int row = srow;
    int t = j >> 1;
    float4 v = ((const float4*)(x + (size_t)t * DMODEL))[threadIdx.x];
    u16x4 o = { f2bf(v.x), f2bf(v.y), f2bf(v.z), f2bf(v.w) };
    *(u16x4*)(Abf + (size_t)row * DMODEL + threadIdx.x * 4) = o;
}

// ---------------- GEMM1: act = silu(A @ Win1^T) * (A @ Win2^T) ----------------
// BM=128 x BN=64 act-cols (x2 SwiGLU halves), BK=64 (16 barrier round-trips).
// Grid 2048 = e(8) x mg(8) x nt(32, fastest -> A-tile L2 reuse across adjacent blocks).
// Each block loops mt = mg, mg+8, ... while live (no dead blocks, any expert skew ok).
// launch_bounds(256,4): ~60 VGPR + 64 AGPR <= 128 -> 4 blocks/CU, 32KB LDS x4 = 128KB.
__global__ __launch_bounds__(256, 4)
void gemm1_kernel(const u16* __restrict__ Abf, const u16* __restrict__ winbf,
                  u16* __restrict__ act, const int* __restrict__ offs) {
    int bid = blockIdx.x;
    int nt = bid & 31;
    int mg = (bid >> 5) & 7;
    int e  = bid >> 8;
    int cnt = offs[e + 1] - offs[e];
    int n0 = nt * 64;
    const u16* wb = winbf + (size_t)e * (2 * DFF) * DMODEL;

    __shared__ u16 lsA[128 * 64];
    __shared__ u16 lsB[2][64 * 64];

    int tid = threadIdx.x, lane = tid & 63, wave = tid >> 6;
    int wm = wave >> 1, wn = wave & 1;
    int s_r8 = lane >> 3;                       // row within 8-row chunk
    int s_cb = ((lane & 7) ^ (lane >> 3)) * 8;  // swizzled source col-block (elements)

    for (int mt = mg; mt * 128 < cnt; mt += 8) {
        int row0 = offs[e] + mt * 128;
        f32x4 acc[2][4][2];
        f32x4 zero = {0.f, 0.f, 0.f, 0.f};
#pragma unroll
        for (int h = 0; h < 2; ++h)
#pragma unroll
            for (int mi = 0; mi < 4; ++mi)
#pragma unroll
                for (int ni = 0; ni < 2; ++ni) acc[h][mi][ni] = zero;

        for (int kk = 0; kk < DMODEL / 64; ++kk) {
            int k0 = kk * 64;
            // A tile 128x64: 4 issues/wave, 8 rows each
#pragma unroll
            for (int q = 0; q < 4; ++q) {
                int R0 = wave * 32 + q * 8;
                g2l16(Abf + (size_t)(row0 + R0 + s_r8) * DMODEL + k0 + s_cb, &lsA[R0 * 64]);
            }
            // B tiles (h1 rows n0.., h2 rows DFF+n0..): 2 issues/wave per half
#pragma unroll
            for (int h = 0; h < 2; ++h)
#pragma unroll
                for (int q = 0; q < 2; ++q) {
                    int R0 = wave * 16 + q * 8;
                    g2l16(wb + (size_t)(h * DFF + n0 + R0 + s_r8) * DMODEL + k0 + s_cb,
                          &lsB[h][R0 * 64]);
                }
            __syncthreads();
#pragma unroll
            for (int kh = 0; kh < 2; ++kh) {
                int cb = kh * 4 + (lane >> 4);
                bf16x8 afr[4];
#pragma unroll
                for (int mi = 0; mi < 4; ++mi)
                    afr[mi] = *(const bf16x8*)&lsA[idx64(wm * 64 + mi * 16 + (lane & 15), cb)];
#pragma unroll
                for (int h = 0; h < 2; ++h)
#pragma unroll
                    for (int ni = 0; ni < 2; ++ni) {
                        bf16x8 bfr = *(const bf16x8*)&lsB[h][idx64(wn * 32 + ni * 16 + (lane & 15), cb)];
#pragma unroll
                        for (int mi = 0; mi < 4; ++mi)
                            acc[h][mi][ni] = __builtin_amdgcn_mfma_f32_16x16x32_bf16(
                                afr[mi], bfr, acc[h][mi][ni], 0, 0, 0);
                    }
            }
            __syncthreads();
        }
        // epilogue: act = silu(h1) * h2, store bf16
        int mmax = cnt - mt * 128;
#pragma unroll
        for (int mi = 0; mi < 4; ++mi)
#pragma unroll
            for (int i = 0; i < 4; ++i) {
                int rl = wm * 64 + mi * 16 + (lane >> 4) * 4 + i;
                if (rl < mmax) {
                    size_t rp = (size_t)(row0 + rl) * DFF;
#pragma unroll
                    for (int ni = 0; ni < 2; ++ni) {
                        int col = n0 + wn * 32 + ni * 16 + (lane & 15);
                        float a = acc[0][mi][ni][i];
                        float b = acc[1][mi][ni][i];
                        float sv = a / (1.0f + __expf(-a));
                        act[rp + col] = f2bf(sv * b);
                    }
                }
            }
    }
}

// ---------------- GEMM2: y = act @ Wout^T, split-K=2, bf16 stores ----------------
// BM=128 x BN=128, BK=64, K=1024 per kc. Grid 1024 = e(8) x kc(2) x mg(8) x nt(8).
__global__ __launch_bounds__(256, 4)
void gemm2_kernel(const u16* __restrict__ act, const u16* __restrict__ woutbf,
                  u16* __restrict__ ybA, u16* __restrict__ ybB,
                  const int* __restrict__ offs) {
    int bid = blockIdx.x;
    int nt = bid & 7;
    int mg = (bid >> 3) & 7;
    int kc = (bid >> 6) & 1;
    int e  = bid >> 7;
    int cnt = offs[e + 1] - offs[e];
    int n0 = nt * 128;
    const u16* wb = woutbf + (size_t)e * DMODEL * DFF;

    __shared__ u16 lsA[128 * 64];
    __shared__ u16 lsB[128 * 64];

    int tid = threadIdx.x, lane = tid & 63, wave = tid >> 6;
    int wm = wave >> 1, wn = wave & 1;
    int s_r8 = lane >> 3;
    int s_cb = ((lane & 7) ^ (lane >> 3)) * 8;
    u16* yb = kc ? ybB : ybA;

    for (int mt = mg; mt * 128 < cnt; mt += 8) {
        int row0 = offs[e] + mt * 128;
        f32x4 acc[4][4];
        f32x4 zero = {0.f, 0.f, 0.f, 0.f};
#pragma unroll
        for (int mi = 0; mi < 4; ++mi)
#pragma unroll
            for (int ni = 0; ni < 4; ++ni) acc[mi][ni] = zero;

        for (int kk = kc * 16; kk < kc * 16 + 16; ++kk) {
            int k0 = kk * 64;
#pragma unroll
            for (int q = 0; q < 4; ++q) {
                int R0 = wave * 32 + q * 8;
                g2l16(act + (size_t)(row0 + R0 + s_r8) * DFF + k0 + s_cb, &lsA[R0 * 64]);
                g2l16(wb + (size_t)(n0 + R0 + s_r8) * DFF + k0 + s_cb, &lsB[R0 * 64]);
            }
            __syncthreads();
#pragma unroll
            for (int kh = 0; kh < 2; ++kh) {
                int cb = kh * 4 + (lane >> 4);
                bf16x8 afr[4];
#pragma unroll
                for (int mi = 0; mi < 4; ++mi)
                    afr[mi] = *(const bf16x8*)&lsA[idx64(wm * 64 + mi * 16 + (lane & 15), cb)];
#pragma unroll
                for (int ni = 0; ni < 4; ++ni) {
                    bf16x8 bfr = *(const bf16x8*)&lsB[idx64(wn * 64 + ni * 16 + (lane & 15), cb)];
#pragma unroll
                    for (int mi = 0; mi < 4; ++mi)
                        acc[mi][ni] = __builtin_amdgcn_mfma_f32_16x16x32_bf16(
                            afr[mi], bfr, acc[mi][ni], 0, 0, 0);
                }
            }
            __syncthreads();
        }
        int mmax = cnt - mt * 128;
#pragma unroll
        for (int mi = 0; mi < 4; ++mi)
#pragma unroll
            for (int i = 0; i < 4; ++i) {
                int rl = wm * 64 + mi * 16 + (lane >> 4) * 4 + i;
                if (rl < mmax) {
                    u16* yrow = yb + (size_t)(row0 + rl) * DMODEL;
#pragma unroll
                    for (int ni = 0; ni < 4; ++ni) {
                        int col = n0 + wn * 64 + ni * 16 + (lane & 15);
                        yrow[col] = f2bf(acc[mi][ni][i]);
                    }
                }
            }
    }
}

// ---------------- combine: out[t] = g0*(y0a+y0b) + g1*(y1a+y1b) ----------------
__global__ void combine_kernel(const u16* __restrict__ ybA, const u16* __restrict__ ybB,
                               const int* __restrict__ inv, const float* __restrict__ tok_gate,
                               float* __restrict__ out) {
    int t = blockIdx.x;
    int tid = threadIdx.x;                // 256
    __shared__ int sr0, sr1;
    __shared__ float sg0, sg1;
    if (tid == 0) {
        sr0 = inv[t * 2];  sr1 = inv[t * 2 + 1];
        sg0 = tok_gate[t * 2];  sg1 = tok_gate[t * 2 + 1];
    }
    __syncthreads();
    int d = tid * 4;
    u16x4 a0 = *(const u16x4*)(ybA + (size_t)sr0 * DMODEL + d);
    u16x4 b0 = *(const u16x4*)(ybB + (size_t)sr0 * DMODEL + d);
    u16x4 a1 = *(const u16x4*)(ybA + (size_t)sr1 * DMODEL + d);
    u16x4 b1 = *(const u16x4*)(ybB + (size_t)sr1 * DMODEL + d);
    float4 o;
    o.x = sg0 * (bf2f(a0.x) + bf2f(b0.x)) + sg1 * (bf2f(a1.x) + bf2f(b1.x));
    o.y = sg0 * (bf2f(a0.y) + bf2f(b0.y)) + sg1 * (bf2f(a1.y) + bf2f(b1.y));
    o.z = sg0 * (bf2f(a0.z) + bf2f(b0.z)) + sg1 * (bf2f(a1.z) + bf2f(b1.z));
    o.w = sg0 * (bf2f(a0.w) + bf2f(b0.w)) + sg1 * (bf2f(a1.w) + bf2f(b1.w));
    *(float4*)(out + (size_t)t * DMODEL + d) = o;
}

// ---------------- launch ----------------
extern "C" void kernel_launch(void* const* d_in, const int* in_sizes, int n_in,
                              void* d_out, int out_size, void* d_ws, size_t ws_size,
                              hipStream_t stream) {
    const float* x    = (const float*)d_in[0];   // [4096, 1024]
    const float* rw   = (const float*)d_in[1];   // [8, 1024]
    const float* win  = (const float*)d_in[2];   // [8, 4096, 1024]
    const float* wout = (const float*)d_in[3];   // [8, 1024, 2048]
    float* out    = (float*)d_out;               // [4096, 1024]
    float* logits = out + (size_t)N_TOK * DMODEL; // [4096, 8]

    char* ws = (char*)d_ws;
    size_t o = 0;
    auto alloc = [&](size_t bytes) -> void* {
        void* p = ws + o;
        o = (o + bytes + 255) & ~(size_t)255;
        return p;
    };
    u16*   Abf      = (u16*)  alloc((size_t)ROWS_PAD * DMODEL * 2);        // 17.0 MB
    u16*   actbuf   = (u16*)  alloc((size_t)ROWS_PAD * DFF * 2);           // 34.1 MB
    u16*   winbf    = (u16*)  alloc((size_t)N_EXP * 2 * DFF * DMODEL * 2); // 67.1 MB
    u16*   woutbf   = (u16*)  alloc((size_t)N_EXP * DMODEL * DFF * 2);     // 33.6 MB
    int*   offs     = (int*)  alloc(16 * 4);
    int*   cursor   = (int*)  alloc(N_EXP * 4);
    int*   inv      = (int*)  alloc(N_SLOTS * 4);
    int*   tok_exp  = (int*)  alloc(N_SLOTS * 4);
    float* tok_gate = (float*)alloc(N_SLOTS * 4);
    // ybA/ybB alias winbf: winbf is dead after gemm1, yb needs 2x17 MB
    u16*   ybA      = winbf;
    u16*   ybB      = winbf + (size_t)ROWS_PAD * DMODEL;
    (void)ws_size; (void)in_sizes; (void)n_in; (void)out_size;

    cvt_router_kernel<<<CVT_BLOCKS + RTR_BLOCKS, 256, 0, stream>>>(
        (const float4*)win, (const float4*)wout, (u16x8*)winbf, (u16x8*)woutbf,
        x, rw, logits, tok_exp, tok_gate);
    scan_kernel<<<1, 256, 0, stream>>>(tok_exp, offs, cursor);
    gather_kernel<<<N_SLOTS, 256, 0, stream>>>(x, tok_exp, offs, cursor, Abf, inv);
    gemm1_kernel<<<8 * 8 * 32, 256, 0, stream>>>(Abf, winbf, actbuf, offs);
    gemm2_kernel<<<8 * 2 * 8 * 8, 256, 0, stream>>>(actbuf, woutbf, ybA, ybB, offs);
    combine_kernel<<<N_TOK, 256, 0, stream>>>(ybA, ybB, inv, tok_gate, out);
}

// Round 7
// 460.037 us; speedup vs baseline: 1.2409x; 1.2007x over previous
//
#include <hip/hip_runtime.h>
#include <stdint.h>

#define N_TOK   4096
#define DMODEL  1024
#define DFF     2048
#define N_EXP   8
#define N_SLOTS (N_TOK * 2)        // 8192 (every token has exactly 2 expert slots)
#define ROWS_PAD (N_SLOTS + 128)   // padding so tile-tail OOB reads stay in-bounds

typedef __bf16 bf16x8 __attribute__((ext_vector_type(8)));
typedef float  f32x4  __attribute__((ext_vector_type(4)));
typedef unsigned short u16;
typedef unsigned short u16x8 __attribute__((ext_vector_type(8)));
typedef unsigned short u16x4 __attribute__((ext_vector_type(4)));

__device__ __forceinline__ u16 f2bf(float f) {
    union { float f; uint32_t u; } v; v.f = f;
    uint32_t r = v.u + 0x7FFFu + ((v.u >> 16) & 1u);  // RTNE
    return (u16)(r >> 16);
}
__device__ __forceinline__ float bf2f(u16 u) {
    union { uint32_t u; float f; } v; v.u = ((uint32_t)u) << 16;
    return v.f;
}

// async 16B/lane global->LDS. LDS dest is wave-uniform base + lane*16 (m104 caveat).
__device__ __forceinline__ void g2l16(const void* gp, void* lp) {
    auto g = reinterpret_cast<const __attribute__((address_space(1))) unsigned int*>(
        reinterpret_cast<uintptr_t>(gp));
    auto l = reinterpret_cast<__attribute__((address_space(3))) unsigned int*>(
        reinterpret_cast<uintptr_t>(lp));
    __builtin_amdgcn_global_load_lds(g, l, 16, 0, 0);
}

// ---- XOR swizzle for 64-u16-wide (128B-row) LDS tiles: 8 col-blocks of 16B ----
// slot(r,cb) = cb ^ (r&7). Frag reads land 2 lanes/bank (free, m136; verified R6:
// SQ_LDS_BANK_CONFLICT == 0).
__device__ __forceinline__ int idx64(int r, int cb) {
    return r * 64 + ((cb ^ (r & 7)) * 8);
}

// ---------------- fused weight-cvt + router (one dispatch) ----------------
#define WIN_V8  (N_EXP * 2 * DFF * DMODEL / 8)   // 4194304
#define WOUT_V8 (N_EXP * DMODEL * DFF / 8)       // 2097152
#define CVT_BLOCKS ((WIN_V8 + WOUT_V8) / 256)    // 24576
#define RTR_BLOCKS (N_TOK / 4)                   // 1024 (4 waves/block, 1 token/wave)

__global__ void cvt_router_kernel(const float4* __restrict__ win, const float4* __restrict__ wout,
                                  u16x8* __restrict__ winbf, u16x8* __restrict__ woutbf,
                                  const float* __restrict__ x, const float* __restrict__ rw,
                                  float* __restrict__ logits, int* __restrict__ tok_expert,
                                  float* __restrict__ tok_gate) {
    int bid = blockIdx.x;
    if (bid < CVT_BLOCKS) {
        int i = bid * 256 + threadIdx.x;
        const float4* s; u16x8* d; int k;
        if (i < WIN_V8) { s = win;  d = winbf;  k = i; }
        else            { s = wout; d = woutbf; k = i - WIN_V8; }
        float4 a = s[k * 2];
        float4 b = s[k * 2 + 1];
        u16x8 o = { f2bf(a.x), f2bf(a.y), f2bf(a.z), f2bf(a.w),
                    f2bf(b.x), f2bf(b.y), f2bf(b.z), f2bf(b.w) };
        d[k] = o;
        return;
    }
    // router: one wave per token, fp32 logits, exact top-2 (ties -> lowest index)
    int t = (bid - CVT_BLOCKS) * 4 + (threadIdx.x >> 6);
    int lane = threadIdx.x & 63;
    const float* xr = x + (size_t)t * DMODEL;
    float acc[N_EXP];
#pragma unroll
    for (int e = 0; e < N_EXP; ++e) acc[e] = 0.f;
    for (int i = 0; i < DMODEL / 64; ++i) {
        int k = lane + i * 64;
        float xv = xr[k];
#pragma unroll
        for (int e = 0; e < N_EXP; ++e) acc[e] += xv * rw[e * DMODEL + k];
    }
#pragma unroll
    for (int e = 0; e < N_EXP; ++e) {
        float v = acc[e];
        for (int off = 32; off > 0; off >>= 1) v += __shfl_down(v, off, 64);
        acc[e] = v;
    }
    if (lane == 0) {
        float* lg = logits + (size_t)t * N_EXP;
#pragma unroll
        for (int e = 0; e < N_EXP; ++e) lg[e] = acc[e];
        int e0 = 0; float v0 = acc[0];
#pragma unroll
        for (int e = 1; e < N_EXP; ++e) if (acc[e] > v0) { v0 = acc[e]; e0 = e; }
        int e1 = -1; float v1 = -3.0e38f;
#pragma unroll
        for (int e = 0; e < N_EXP; ++e) if (e != e0 && acc[e] > v1) { v1 = acc[e]; e1 = e; }
        float ex = expf(v1 - v0);
        tok_expert[t * 2 + 0] = e0;  tok_gate[t * 2 + 0] = 1.0f / (1.0f + ex);
        tok_expert[t * 2 + 1] = e1;  tok_gate[t * 2 + 1] = ex / (1.0f + ex);
    }
}

// ---------------- scan: atomic-free counting sort -> offs[] and inv[] ----------------
// One block, 256 threads, 32 slots/thread. Two passes + 8-lane serial prefix.
// Replaces the 8192 contended global atomics that made gather_kernel cost ~97us (R6).
__global__ void scan_kernel(const int* __restrict__ tok_expert, int* __restrict__ offs,
                            int* __restrict__ inv) {
    __shared__ int cnt[N_EXP][257];   // [e][t] per-thread counts; [e][256] = expert total
    __shared__ int soffs[N_EXP];
    int tid = threadIdx.x;            // 256
    int base = tid * 32;
    int loc[N_EXP];
#pragma unroll
    for (int e = 0; e < N_EXP; ++e) loc[e] = 0;
    for (int i = 0; i < 32; ++i) {
        int ex = tok_expert[base + i];
#pragma unroll
        for (int e = 0; e < N_EXP; ++e) loc[e] += (ex == e);
    }
#pragma unroll
    for (int e = 0; e < N_EXP; ++e) cnt[e][tid] = loc[e];
    __syncthreads();
    if (tid < N_EXP) {                // serial exclusive prefix over 256 thread-counts
        int running = 0;
        for (int t = 0; t < 256; ++t) { int c = cnt[tid][t]; cnt[tid][t] = running; running += c; }
        cnt[tid][256] = running;
    }
    __syncthreads();
    if (tid == 0) {
        int s = 0;
        for (int e = 0; e < N_EXP; ++e) { offs[e] = s; soffs[e] = s; s += cnt[e][256]; }
        offs[N_EXP] = s;
    }
    __syncthreads();
#pragma unroll
    for (int e = 0; e < N_EXP; ++e) loc[e] = 0;   // reuse as local rank counters
    for (int i = 0; i < 32; ++i) {
        int ex = tok_expert[base + i];
        int row = 0;
#pragma unroll
        for (int e = 0; e < N_EXP; ++e)
            if (ex == e) { row = soffs[e] + cnt[e][tid] + loc[e]; loc[e]++; }
        inv[base + i] = row;
    }
}

// ---------------- gather: pure copy, one block per TOKEN (x row read once) ----------------
__global__ void gather_kernel(const float* __restrict__ x, const int* __restrict__ inv,
                              u16* __restrict__ Abf) {
    int t = blockIdx.x;                   // token
    int r0 = inv[t * 2];
    int r1 = inv[t * 2 + 1];
    float4 v = ((const float4*)(x + (size_t)t * DMODEL))[threadIdx.x];
    u16x4 o = { f2bf(v.x), f2bf(v.y), f2bf(v.z), f2bf(v.w) };
    *(u16x4*)(Abf + (size_t)r0 * DMODEL + threadIdx.x * 4) = o;
    *(u16x4*)(Abf + (size_t)r1 * DMODEL + threadIdx.x * 4) = o;
}

// ---------------- GEMM1: act = silu(A @ Win1^T) * (A @ Win2^T) ----------------
// BM=128 x BN=64 act-cols (x2 SwiGLU halves), BK=64 (16 barrier round-trips).
// Grid 2048 = e(8) x mg(8) x nt(32, fastest -> A-tile L2 reuse across adjacent blocks).
__global__ __launch_bounds__(256, 4)
void gemm1_kernel(const u16* __restrict__ Abf, const u16* __restrict__ winbf,
                  u16* __restrict__ act, const int* __restrict__ offs) {
    int bid = blockIdx.x;
    int nt = bid & 31;
    int mg = (bid >> 5) & 7;
    int e  = bid >> 8;
    int cnt = offs[e + 1] - offs[e];
    int n0 = nt * 64;
    const u16* wb = winbf + (size_t)e * (2 * DFF) * DMODEL;

    __shared__ u16 lsA[128 * 64];
    __shared__ u16 lsB[2][64 * 64];

    int tid = threadIdx.x, lane = tid & 63, wave = tid >> 6;
    int wm = wave >> 1, wn = wave & 1;
    int s_r8 = lane >> 3;                       // row within 8-row chunk
    int s_cb = ((lane & 7) ^ (lane >> 3)) * 8;  // swizzled source col-block (elements)

    for (int mt = mg; mt * 128 < cnt; mt += 8) {
        int row0 = offs[e] + mt * 128;
        f32x4 acc[2][4][2];
        f32x4 zero = {0.f, 0.f, 0.f, 0.f};
#pragma unroll
        for (int h = 0; h < 2; ++h)
#pragma unroll
            for (int mi = 0; mi < 4; ++mi)
#pragma unroll
                for (int ni = 0; ni < 2; ++ni) acc[h][mi][ni] = zero;

        for (int kk = 0; kk < DMODEL / 64; ++kk) {
            int k0 = kk * 64;
#pragma unroll
            for (int q = 0; q < 4; ++q) {
                int R0 = wave * 32 + q * 8;
                g2l16(Abf + (size_t)(row0 + R0 + s_r8) * DMODEL + k0 + s_cb, &lsA[R0 * 64]);
            }
#pragma unroll
            for (int h = 0; h < 2; ++h)
#pragma unroll
                for (int q = 0; q < 2; ++q) {
                    int R0 = wave * 16 + q * 8;
                    g2l16(wb + (size_t)(h * DFF + n0 + R0 + s_r8) * DMODEL + k0 + s_cb,
                          &lsB[h][R0 * 64]);
                }
            __syncthreads();
#pragma unroll
            for (int kh = 0; kh < 2; ++kh) {
                int cb = kh * 4 + (lane >> 4);
                bf16x8 afr[4];
#pragma unroll
                for (int mi = 0; mi < 4; ++mi)
                    afr[mi] = *(const bf16x8*)&lsA[idx64(wm * 64 + mi * 16 + (lane & 15), cb)];
#pragma unroll
                for (int h = 0; h < 2; ++h)
#pragma unroll
                    for (int ni = 0; ni < 2; ++ni) {
                        bf16x8 bfr = *(const bf16x8*)&lsB[h][idx64(wn * 32 + ni * 16 + (lane & 15), cb)];
#pragma unroll
                        for (int mi = 0; mi < 4; ++mi)
                            acc[h][mi][ni] = __builtin_amdgcn_mfma_f32_16x16x32_bf16(
                                afr[mi], bfr, acc[h][mi][ni], 0, 0, 0);
                    }
            }
            __syncthreads();
        }
        int mmax = cnt - mt * 128;
#pragma unroll
        for (int mi = 0; mi < 4; ++mi)
#pragma unroll
            for (int i = 0; i < 4; ++i) {
                int rl = wm * 64 + mi * 16 + (lane >> 4) * 4 + i;
                if (rl < mmax) {
                    size_t rp = (size_t)(row0 + rl) * DFF;
#pragma unroll
                    for (int ni = 0; ni < 2; ++ni) {
                        int col = n0 + wn * 32 + ni * 16 + (lane & 15);
                        float a = acc[0][mi][ni][i];
                        float b = acc[1][mi][ni][i];
                        float sv = a / (1.0f + __expf(-a));
                        act[rp + col] = f2bf(sv * b);
                    }
                }
            }
    }
}

// ---------------- GEMM2: y = act @ Wout^T, split-K=2, bf16 stores ----------------
// BM=128 x BN=128, BK=64, K=1024 per kc. Grid 1024 = e(8) x kc(2) x mg(8) x nt(8).
__global__ __launch_bounds__(256, 4)
void gemm2_kernel(const u16* __restrict__ act, const u16* __restrict__ woutbf,
                  u16* __restrict__ ybA, u16* __restrict__ ybB,
                  const int* __restrict__ offs) {
    int bid = blockIdx.x;
    int nt = bid & 7;
    int mg = (bid >> 3) & 7;
    int kc = (bid >> 6) & 1;
    int e  = bid >> 7;
    int cnt = offs[e + 1] - offs[e];
    int n0 = nt * 128;
    const u16* wb = woutbf + (size_t)e * DMODEL * DFF;

    __shared__ u16 lsA[128 * 64];
    __shared__ u16 lsB[128 * 64];

    int tid = threadIdx.x, lane = tid & 63, wave = tid >> 6;
    int wm = wave >> 1, wn = wave & 1;
    int s_r8 = lane >> 3;
    int s_cb = ((lane & 7) ^ (lane >> 3)) * 8;
    u16* yb = kc ? ybB : ybA;

    for (int mt = mg; mt * 128 < cnt; mt += 8) {
        int row0 = offs[e] + mt * 128;
        f32x4 acc[4][4];
        f32x4 zero = {0.f, 0.f, 0.f, 0.f};
#pragma unroll
        for (int mi = 0; mi < 4; ++mi)
#pragma unroll
            for (int ni = 0; ni < 4; ++ni) acc[mi][ni] = zero;

        for (int kk = kc * 16; kk < kc * 16 + 16; ++kk) {
            int k0 = kk * 64;
#pragma unroll
            for (int q = 0; q < 4; ++q) {
                int R0 = wave * 32 + q * 8;
                g2l16(act + (size_t)(row0 + R0 + s_r8) * DFF + k0 + s_cb, &lsA[R0 * 64]);
                g2l16(wb + (size_t)(n0 + R0 + s_r8) * DFF + k0 + s_cb, &lsB[R0 * 64]);
            }
            __syncthreads();
#pragma unroll
            for (int kh = 0; kh < 2; ++kh) {
                int cb = kh * 4 + (lane >> 4);
                bf16x8 afr[4];
#pragma unroll
                for (int mi = 0; mi < 4; ++mi)
                    afr[mi] = *(const bf16x8*)&lsA[idx64(wm * 64 + mi * 16 + (lane & 15), cb)];
#pragma unroll
                for (int ni = 0; ni < 4; ++ni) {
                    bf16x8 bfr = *(const bf16x8*)&lsB[idx64(wn * 64 + ni * 16 + (lane & 15), cb)];
#pragma unroll
                    for (int mi = 0; mi < 4; ++mi)
                        acc[mi][ni] = __builtin_amdgcn_mfma_f32_16x16x32_bf16(
                            afr[mi], bfr, acc[mi][ni], 0, 0, 0);
                }
            }
            __syncthreads();
        }
        int mmax = cnt - mt * 128;
#pragma unroll
        for (int mi = 0; mi < 4; ++mi)
#pragma unroll
            for (int i = 0; i < 4; ++i) {
                int rl = wm * 64 + mi * 16 + (lane >> 4) * 4 + i;
                if (rl < mmax) {
                    u16* yrow = yb + (size_t)(row0 + rl) * DMODEL;
#pragma unroll
                    for (int ni = 0; ni < 4; ++ni) {
                        int col = n0 + wn * 64 + ni * 16 + (lane & 15);
                        yrow[col] = f2bf(acc[mi][ni][i]);
                    }
                }
            }
    }
}

// ---------------- combine: out[t] = g0*(y0a+y0b) + g1*(y1a+y1b) ----------------
__global__ void combine_kernel(const u16* __restrict__ ybA, const u16* __restrict__ ybB,
                               const int* __restrict__ inv, const float* __restrict__ tok_gate,
                               float* __restrict__ out) {
    int t = blockIdx.x;
    int tid = threadIdx.x;                // 256
    __shared__ int sr0, sr1;
    __shared__ float sg0, sg1;
    if (tid == 0) {
        sr0 = inv[t * 2];  sr1 = inv[t * 2 + 1];
        sg0 = tok_gate[t * 2];  sg1 = tok_gate[t * 2 + 1];
    }
    __syncthreads();
    int d = tid * 4;
    u16x4 a0 = *(const u16x4*)(ybA + (size_t)sr0 * DMODEL + d);
    u16x4 b0 = *(const u16x4*)(ybB + (size_t)sr0 * DMODEL + d);
    u16x4 a1 = *(const u16x4*)(ybA + (size_t)sr1 * DMODEL + d);
    u16x4 b1 = *(const u16x4*)(ybB + (size_t)sr1 * DMODEL + d);
    float4 o;
    o.x = sg0 * (bf2f(a0.x) + bf2f(b0.x)) + sg1 * (bf2f(a1.x) + bf2f(b1.x));
    o.y = sg0 * (bf2f(a0.y) + bf2f(b0.y)) + sg1 * (bf2f(a1.y) + bf2f(b1.y));
    o.z = sg0 * (bf2f(a0.z) + bf2f(b0.z)) + sg1 * (bf2f(a1.z) + bf2f(b1.z));
    o.w = sg0 * (bf2f(a0.w) + bf2f(b0.w)) + sg1 * (bf2f(a1.w) + bf2f(b1.w));
    *(float4*)(out + (size_t)t * DMODEL + d) = o;
}

// ---------------- launch ----------------
extern "C" void kernel_launch(void* const* d_in, const int* in_sizes, int n_in,
                              void* d_out, int out_size, void* d_ws, size_t ws_size,
                              hipStream_t stream) {
    const float* x    = (const float*)d_in[0];   // [4096, 1024]
    const float* rw   = (const float*)d_in[1];   // [8, 1024]
    const float* win  = (const float*)d_in[2];   // [8, 4096, 1024]
    const float* wout = (const float*)d_in[3];   // [8, 1024, 2048]
    float* out    = (float*)d_out;               // [4096, 1024]
    float* logits = out + (size_t)N_TOK * DMODEL; // [4096, 8]

    char* ws = (char*)d_ws;
    size_t o = 0;
    auto alloc = [&](size_t bytes) -> void* {
        void* p = ws + o;
        o = (o + bytes + 255) & ~(size_t)255;
        return p;
    };
    u16*   Abf      = (u16*)  alloc((size_t)ROWS_PAD * DMODEL * 2);        // 17.0 MB
    u16*   actbuf   = (u16*)  alloc((size_t)ROWS_PAD * DFF * 2);           // 34.1 MB
    u16*   winbf    = (u16*)  alloc((size_t)N_EXP * 2 * DFF * DMODEL * 2); // 67.1 MB
    u16*   woutbf   = (u16*)  alloc((size_t)N_EXP * DMODEL * DFF * 2);     // 33.6 MB
    int*   offs     = (int*)  alloc(16 * 4);
    int*   inv      = (int*)  alloc(N_SLOTS * 4);
    int*   tok_exp  = (int*)  alloc(N_SLOTS * 4);
    float* tok_gate = (float*)alloc(N_SLOTS * 4);
    // ybA/ybB alias winbf: winbf is dead after gemm1, yb needs 2x17 MB
    u16*   ybA      = winbf;
    u16*   ybB      = winbf + (size_t)ROWS_PAD * DMODEL;
    (void)ws_size; (void)in_sizes; (void)n_in; (void)out_size;

    cvt_router_kernel<<<CVT_BLOCKS + RTR_BLOCKS, 256, 0, stream>>>(
        (const float4*)win, (const float4*)wout, (u16x8*)winbf, (u16x8*)woutbf,
        x, rw, logits, tok_exp, tok_gate);
    scan_kernel<<<1, 256, 0, stream>>>(tok_exp, offs, inv);
    gather_kernel<<<N_TOK, 256, 0, stream>>>(x, inv, Abf);
    gemm1_kernel<<<8 * 8 * 32, 256, 0, stream>>>(Abf, winbf, actbuf, offs);
    gemm2_kernel<<<8 * 2 * 8 * 8, 256, 0, stream>>>(actbuf, woutbf, ybA, ybB, offs);
    combine_kernel<<<N_TOK, 256, 0, stream>>>(ybA, ybB, inv, tok_gate, out);
}

// Round 8
// 430.287 us; speedup vs baseline: 1.3267x; 1.0691x over previous
//
#include <hip/hip_runtime.h>
#include <stdint.h>

#define N_TOK   4096
#define DMODEL  1024
#define DFF     2048
#define N_EXP   8
#define N_SLOTS (N_TOK * 2)        // 8192 (every token has exactly 2 expert slots)
#define ROWS_PAD (N_SLOTS + 128)   // padding so tile-tail OOB reads stay in-bounds
#define MAX_TILES 72               // sum ceil(cnt_e/128) <= 71 for any routing

typedef __bf16 bf16x8 __attribute__((ext_vector_type(8)));
typedef float  f32x4  __attribute__((ext_vector_type(4)));
typedef unsigned short u16;
typedef unsigned short u16x8 __attribute__((ext_vector_type(8)));
typedef unsigned short u16x4 __attribute__((ext_vector_type(4)));

__device__ __forceinline__ u16 f2bf(float f) {
    union { float f; uint32_t u; } v; v.f = f;
    uint32_t r = v.u + 0x7FFFu + ((v.u >> 16) & 1u);  // RTNE
    return (u16)(r >> 16);
}
__device__ __forceinline__ float bf2f(u16 u) {
    union { uint32_t u; float f; } v; v.u = ((uint32_t)u) << 16;
    return v.f;
}

// async 16B/lane global->LDS. LDS dest is wave-uniform base + lane*16 (m104 caveat).
__device__ __forceinline__ void g2l16(const void* gp, void* lp) {
    auto g = reinterpret_cast<const __attribute__((address_space(1))) unsigned int*>(
        reinterpret_cast<uintptr_t>(gp));
    auto l = reinterpret_cast<__attribute__((address_space(3))) unsigned int*>(
        reinterpret_cast<uintptr_t>(lp));
    __builtin_amdgcn_global_load_lds(g, l, 16, 0, 0);
}

// ---- XOR swizzle for 64-u16-wide (128B-row) LDS tiles: 8 col-blocks of 16B ----
// slot(r,cb) = cb ^ (r&7). Verified R6/R7: SQ_LDS_BANK_CONFLICT == 0.
__device__ __forceinline__ int idx64(int r, int cb) {
    return r * 64 + ((cb ^ (r & 7)) * 8);
}

// ---------------- fused weight-cvt + router (one dispatch) ----------------
#define WIN_V8  (N_EXP * 2 * DFF * DMODEL / 8)   // 4194304
#define WOUT_V8 (N_EXP * DMODEL * DFF / 8)       // 2097152
#define CVT_BLOCKS ((WIN_V8 + WOUT_V8) / 256)    // 24576
#define RTR_BLOCKS (N_TOK / 4)                   // 1024 (4 waves/block, 1 token/wave)

__global__ void cvt_router_kernel(const float4* __restrict__ win, const float4* __restrict__ wout,
                                  u16x8* __restrict__ winbf, u16x8* __restrict__ woutbf,
                                  const float* __restrict__ x, const float* __restrict__ rw,
                                  float* __restrict__ logits, int* __restrict__ tok_expert,
                                  float* __restrict__ tok_gate) {
    int bid = blockIdx.x;
    if (bid < CVT_BLOCKS) {
        int i = bid * 256 + threadIdx.x;
        const float4* s; u16x8* d; int k;
        if (i < WIN_V8) { s = win;  d = winbf;  k = i; }
        else            { s = wout; d = woutbf; k = i - WIN_V8; }
        float4 a = s[k * 2];
        float4 b = s[k * 2 + 1];
        u16x8 o = { f2bf(a.x), f2bf(a.y), f2bf(a.z), f2bf(a.w),
                    f2bf(b.x), f2bf(b.y), f2bf(b.z), f2bf(b.w) };
        d[k] = o;
        return;
    }
    // router: one wave per token, fp32 logits, exact top-2 (ties -> lowest index)
    int t = (bid - CVT_BLOCKS) * 4 + (threadIdx.x >> 6);
    int lane = threadIdx.x & 63;
    const float* xr = x + (size_t)t * DMODEL;
    float acc[N_EXP];
#pragma unroll
    for (int e = 0; e < N_EXP; ++e) acc[e] = 0.f;
    for (int i = 0; i < DMODEL / 64; ++i) {
        int k = lane + i * 64;
        float xv = xr[k];
#pragma unroll
        for (int e = 0; e < N_EXP; ++e) acc[e] += xv * rw[e * DMODEL + k];
    }
#pragma unroll
    for (int e = 0; e < N_EXP; ++e) {
        float v = acc[e];
        for (int off = 32; off > 0; off >>= 1) v += __shfl_down(v, off, 64);
        acc[e] = v;
    }
    if (lane == 0) {
        float* lg = logits + (size_t)t * N_EXP;
#pragma unroll
        for (int e = 0; e < N_EXP; ++e) lg[e] = acc[e];
        int e0 = 0; float v0 = acc[0];
#pragma unroll
        for (int e = 1; e < N_EXP; ++e) if (acc[e] > v0) { v0 = acc[e]; e0 = e; }
        int e1 = -1; float v1 = -3.0e38f;
#pragma unroll
        for (int e = 0; e < N_EXP; ++e) if (e != e0 && acc[e] > v1) { v1 = acc[e]; e1 = e; }
        float ex = expf(v1 - v0);
        tok_expert[t * 2 + 0] = e0;  tok_gate[t * 2 + 0] = 1.0f / (1.0f + ex);
        tok_expert[t * 2 + 1] = e1;  tok_gate[t * 2 + 1] = ex / (1.0f + ex);
    }
}

// ---------------- scan: counting sort -> offs[], inv[], flat m-tile table ----------------
// One block, 256 threads, atomic-free. tiletab[0] = ntiles; entry i at [4+4i]:
// {expert, row0, rows, pad}. Uniform per-block work for both GEMMs (no dead blocks,
// no mt-loop imbalance, correct under any expert skew).
__global__ void scan_kernel(const int* __restrict__ tok_expert, int* __restrict__ offs,
                            int* __restrict__ inv, int* __restrict__ tiletab) {
    __shared__ int cnt[N_EXP][257];   // [e][t] per-thread counts; [e][256] = expert total
    __shared__ int soffs[N_EXP];
    int tid = threadIdx.x;            // 256
    int base = tid * 32;
    int loc[N_EXP];
#pragma unroll
    for (int e = 0; e < N_EXP; ++e) loc[e] = 0;
    for (int i = 0; i < 32; ++i) {
        int ex = tok_expert[base + i];
#pragma unroll
        for (int e = 0; e < N_EXP; ++e) loc[e] += (ex == e);
    }
#pragma unroll
    for (int e = 0; e < N_EXP; ++e) cnt[e][tid] = loc[e];
    __syncthreads();
    if (tid < N_EXP) {                // serial exclusive prefix over 256 thread-counts
        int running = 0;
        for (int t = 0; t < 256; ++t) { int c = cnt[tid][t]; cnt[tid][t] = running; running += c; }
        cnt[tid][256] = running;
    }
    __syncthreads();
    if (tid == 0) {
        int s = 0;
        for (int e = 0; e < N_EXP; ++e) { offs[e] = s; soffs[e] = s; s += cnt[e][256]; }
        offs[N_EXP] = s;
        int n = 0;
        for (int e = 0; e < N_EXP; ++e) {
            int c = cnt[e][256];
            int r0 = soffs[e];
            for (int m = 0; m * 128 < c; ++m) {
                int rem = c - m * 128;
                tiletab[4 + n * 4 + 0] = e;
                tiletab[4 + n * 4 + 1] = r0 + m * 128;
                tiletab[4 + n * 4 + 2] = rem < 128 ? rem : 128;
                ++n;
            }
        }
        tiletab[0] = n;
    }
    __syncthreads();
#pragma unroll
    for (int e = 0; e < N_EXP; ++e) loc[e] = 0;   // reuse as local rank counters
    for (int i = 0; i < 32; ++i) {
        int ex = tok_expert[base + i];
        int row = 0;
#pragma unroll
        for (int e = 0; e < N_EXP; ++e)
            if (ex == e) { row = soffs[e] + cnt[e][tid] + loc[e]; loc[e]++; }
        inv[base + i] = row;
    }
}

// ---------------- gather: pure copy, one block per TOKEN (x row read once) ----------------
__global__ void gather_kernel(const float* __restrict__ x, const int* __restrict__ inv,
                              u16* __restrict__ Abf) {
    int t = blockIdx.x;                   // token
    int r0 = inv[t * 2];
    int r1 = inv[t * 2 + 1];
    float4 v = ((const float4*)(x + (size_t)t * DMODEL))[threadIdx.x];
    u16x4 o = { f2bf(v.x), f2bf(v.y), f2bf(v.z), f2bf(v.w) };
    *(u16x4*)(Abf + (size_t)r0 * DMODEL + threadIdx.x * 4) = o;
    *(u16x4*)(Abf + (size_t)r1 * DMODEL + threadIdx.x * 4) = o;
}

// ---------------- GEMM1: act = silu(A @ Win1^T) * (A @ Win2^T) ----------------
// BM=128 x BN=64 act-cols (x2 SwiGLU halves), BK=64. One m-tile per block via tiletab.
// Grid MAX_TILES x 32 nt (nt fastest: adjacent blocks share the A-tile in L2).
__global__ __launch_bounds__(256, 4)
void gemm1_kernel(const u16* __restrict__ Abf, const u16* __restrict__ winbf,
                  u16* __restrict__ act, const int* __restrict__ tiletab) {
    int bid = blockIdx.x;
    int nt = bid & 31;
    int ti = bid >> 5;
    if (ti >= tiletab[0]) return;
    int e    = tiletab[4 + ti * 4 + 0];
    int row0 = tiletab[4 + ti * 4 + 1];
    int mmax = tiletab[4 + ti * 4 + 2];
    int n0 = nt * 64;
    const u16* wb = winbf + (size_t)e * (2 * DFF) * DMODEL;

    __shared__ u16 lsA[128 * 64];
    __shared__ u16 lsB[2][64 * 64];

    int tid = threadIdx.x, lane = tid & 63, wave = tid >> 6;
    int wm = wave >> 1, wn = wave & 1;
    int s_r8 = lane >> 3;                       // row within 8-row chunk
    int s_cb = ((lane & 7) ^ (lane >> 3)) * 8;  // swizzled source col-block (elements)

    f32x4 acc[2][4][2];
    f32x4 zero = {0.f, 0.f, 0.f, 0.f};
#pragma unroll
    for (int h = 0; h < 2; ++h)
#pragma unroll
        for (int mi = 0; mi < 4; ++mi)
#pragma unroll
            for (int ni = 0; ni < 2; ++ni) acc[h][mi][ni] = zero;

    for (int kk = 0; kk < DMODEL / 64; ++kk) {
        int k0 = kk * 64;
#pragma unroll
        for (int q = 0; q < 4; ++q) {
            int R0 = wave * 32 + q * 8;
            g2l16(Abf + (size_t)(row0 + R0 + s_r8) * DMODEL + k0 + s_cb, &lsA[R0 * 64]);
        }
#pragma unroll
        for (int h = 0; h < 2; ++h)
#pragma unroll
            for (int q = 0; q < 2; ++q) {
                int R0 = wave * 16 + q * 8;
                g2l16(wb + (size_t)(h * DFF + n0 + R0 + s_r8) * DMODEL + k0 + s_cb,
                      &lsB[h][R0 * 64]);
            }
        __syncthreads();
#pragma unroll
        for (int kh = 0; kh < 2; ++kh) {
            int cb = kh * 4 + (lane >> 4);
            bf16x8 afr[4];
#pragma unroll
            for (int mi = 0; mi < 4; ++mi)
                afr[mi] = *(const bf16x8*)&lsA[idx64(wm * 64 + mi * 16 + (lane & 15), cb)];
#pragma unroll
            for (int h = 0; h < 2; ++h)
#pragma unroll
                for (int ni = 0; ni < 2; ++ni) {
                    bf16x8 bfr = *(const bf16x8*)&lsB[h][idx64(wn * 32 + ni * 16 + (lane & 15), cb)];
#pragma unroll
                    for (int mi = 0; mi < 4; ++mi)
                        acc[h][mi][ni] = __builtin_amdgcn_mfma_f32_16x16x32_bf16(
                            afr[mi], bfr, acc[h][mi][ni], 0, 0, 0);
                }
        }
        __syncthreads();
    }
    // epilogue: act = silu(h1) * h2, store bf16
#pragma unroll
    for (int mi = 0; mi < 4; ++mi)
#pragma unroll
        for (int i = 0; i < 4; ++i) {
            int rl = wm * 64 + mi * 16 + (lane >> 4) * 4 + i;
            if (rl < mmax) {
                size_t rp = (size_t)(row0 + rl) * DFF;
#pragma unroll
                for (int ni = 0; ni < 2; ++ni) {
                    int col = n0 + wn * 32 + ni * 16 + (lane & 15);
                    float a = acc[0][mi][ni][i];
                    float b = acc[1][mi][ni][i];
                    float sv = a / (1.0f + __expf(-a));
                    act[rp + col] = f2bf(sv * b);
                }
            }
        }
}

// ---------------- GEMM2: y = act @ Wout^T, split-K=2, bf16 stores ----------------
// BM=128 x BN=128, BK=64, K=1024 per kc. One m-tile per block via tiletab.
// Grid MAX_TILES x 8 nt x 2 kc (nt/kc fastest: 16 adjacent blocks share the act-tile).
__global__ __launch_bounds__(256, 4)
void gemm2_kernel(const u16* __restrict__ act, const u16* __restrict__ woutbf,
                  u16* __restrict__ ybA, u16* __restrict__ ybB,
                  const int* __restrict__ tiletab) {
    int bid = blockIdx.x;
    int kc = bid & 1;
    int nt = (bid >> 1) & 7;
    int ti = bid >> 4;
    if (ti >= tiletab[0]) return;
    int e    = tiletab[4 + ti * 4 + 0];
    int row0 = tiletab[4 + ti * 4 + 1];
    int mmax = tiletab[4 + ti * 4 + 2];
    int n0 = nt * 128;
    const u16* wb = woutbf + (size_t)e * DMODEL * DFF;

    __shared__ u16 lsA[128 * 64];
    __shared__ u16 lsB[128 * 64];

    int tid = threadIdx.x, lane = tid & 63, wave = tid >> 6;
    int wm = wave >> 1, wn = wave & 1;
    int s_r8 = lane >> 3;
    int s_cb = ((lane & 7) ^ (lane >> 3)) * 8;
    u16* yb = kc ? ybB : ybA;

    f32x4 acc[4][4];
    f32x4 zero = {0.f, 0.f, 0.f, 0.f};
#pragma unroll
    for (int mi = 0; mi < 4; ++mi)
#pragma unroll
        for (int ni = 0; ni < 4; ++ni) acc[mi][ni] = zero;

    for (int kk = kc * 16; kk < kc * 16 + 16; ++kk) {
        int k0 = kk * 64;
#pragma unroll
        for (int q = 0; q < 4; ++q) {
            int R0 = wave * 32 + q * 8;
            g2l16(act + (size_t)(row0 + R0 + s_r8) * DFF + k0 + s_cb, &lsA[R0 * 64]);
            g2l16(wb + (size_t)(n0 + R0 + s_r8) * DFF + k0 + s_cb, &lsB[R0 * 64]);
        }
        __syncthreads();
#pragma unroll
        for (int kh = 0; kh < 2; ++kh) {
            int cb = kh * 4 + (lane >> 4);
            bf16x8 afr[4];
#pragma unroll
            for (int mi = 0; mi < 4; ++mi)
                afr[mi] = *(const bf16x8*)&lsA[idx64(wm * 64 + mi * 16 + (lane & 15), cb)];
#pragma unroll
            for (int ni = 0; ni < 4; ++ni) {
                bf16x8 bfr = *(const bf16x8*)&lsB[idx64(wn * 64 + ni * 16 + (lane & 15), cb)];
#pragma unroll
                for (int mi = 0; mi < 4; ++mi)
                    acc[mi][ni] = __builtin_amdgcn_mfma_f32_16x16x32_bf16(
                        afr[mi], bfr, acc[mi][ni], 0, 0, 0);
            }
        }
        __syncthreads();
    }
#pragma unroll
    for (int mi = 0; mi < 4; ++mi)
#pragma unroll
        for (int i = 0; i < 4; ++i) {
            int rl = wm * 64 + mi * 16 + (lane >> 4) * 4 + i;
            if (rl < mmax) {
                u16* yrow = yb + (size_t)(row0 + rl) * DMODEL;
#pragma unroll
                for (int ni = 0; ni < 4; ++ni) {
                    int col = n0 + wn * 64 + ni * 16 + (lane & 15);
                    yrow[col] = f2bf(acc[mi][ni][i]);
                }
            }
        }
}

// ---------------- combine: out[t] = g0*(y0a+y0b) + g1*(y1a+y1b) ----------------
__global__ void combine_kernel(const u16* __restrict__ ybA, const u16* __restrict__ ybB,
                               const int* __restrict__ inv, const float* __restrict__ tok_gate,
                               float* __restrict__ out) {
    int t = blockIdx.x;
    int tid = threadIdx.x;                // 256
    __shared__ int sr0, sr1;
    __shared__ float sg0, sg1;
    if (tid == 0) {
        sr0 = inv[t * 2];  sr1 = inv[t * 2 + 1];
        sg0 = tok_gate[t * 2];  sg1 = tok_gate[t * 2 + 1];
    }
    __syncthreads();
    int d = tid * 4;
    u16x4 a0 = *(const u16x4*)(ybA + (size_t)sr0 * DMODEL + d);
    u16x4 b0 = *(const u16x4*)(ybB + (size_t)sr0 * DMODEL + d);
    u16x4 a1 = *(const u16x4*)(ybA + (size_t)sr1 * DMODEL + d);
    u16x4 b1 = *(const u16x4*)(ybB + (size_t)sr1 * DMODEL + d);
    float4 o;
    o.x = sg0 * (bf2f(a0.x) + bf2f(b0.x)) + sg1 * (bf2f(a1.x) + bf2f(b1.x));
    o.y = sg0 * (bf2f(a0.y) + bf2f(b0.y)) + sg1 * (bf2f(a1.y) + bf2f(b1.y));
    o.z = sg0 * (bf2f(a0.z) + bf2f(b0.z)) + sg1 * (bf2f(a1.z) + bf2f(b1.z));
    o.w = sg0 * (bf2f(a0.w) + bf2f(b0.w)) + sg1 * (bf2f(a1.w) + bf2f(b1.w));
    *(float4*)(out + (size_t)t * DMODEL + d) = o;
}

// ---------------- launch ----------------
extern "C" void kernel_launch(void* const* d_in, const int* in_sizes, int n_in,
                              void* d_out, int out_size, void* d_ws, size_t ws_size,
                              hipStream_t stream) {
    const float* x    = (const float*)d_in[0];   // [4096, 1024]
    const float* rw   = (const float*)d_in[1];   // [8, 1024]
    const float* win  = (const float*)d_in[2];   // [8, 4096, 1024]
    const float* wout = (const float*)d_in[3];   // [8, 1024, 2048]
    float* out    = (float*)d_out;               // [4096, 1024]
    float* logits = out + (size_t)N_TOK * DMODEL; // [4096, 8]

    char* ws = (char*)d_ws;
    size_t o = 0;
    auto alloc = [&](size_t bytes) -> void* {
        void* p = ws + o;
        o = (o + bytes + 255) & ~(size_t)255;
        return p;
    };
    u16*   Abf      = (u16*)  alloc((size_t)ROWS_PAD * DMODEL * 2);        // 17.0 MB
    u16*   actbuf   = (u16*)  alloc((size_t)ROWS_PAD * DFF * 2);           // 34.1 MB
    u16*   winbf    = (u16*)  alloc((size_t)N_EXP * 2 * DFF * DMODEL * 2); // 67.1 MB
    u16*   woutbf   = (u16*)  alloc((size_t)N_EXP * DMODEL * DFF * 2);     // 33.6 MB
    int*   offs     = (int*)  alloc(16 * 4);
    int*   inv      = (int*)  alloc(N_SLOTS * 4);
    int*   tok_exp  = (int*)  alloc(N_SLOTS * 4);
    float* tok_gate = (float*)alloc(N_SLOTS * 4);
    int*   tiletab  = (int*)  alloc((4 + MAX_TILES * 4) * 4);
    // ybA/ybB alias winbf: winbf is dead after gemm1, yb needs 2x17 MB
    u16*   ybA      = winbf;
    u16*   ybB      = winbf + (size_t)ROWS_PAD * DMODEL;
    (void)ws_size; (void)in_sizes; (void)n_in; (void)out_size;

    cvt_router_kernel<<<CVT_BLOCKS + RTR_BLOCKS, 256, 0, stream>>>(
        (const float4*)win, (const float4*)wout, (u16x8*)winbf, (u16x8*)woutbf,
        x, rw, logits, tok_exp, tok_gate);
    scan_kernel<<<1, 256, 0, stream>>>(tok_exp, offs, inv, tiletab);
    gather_kernel<<<N_TOK, 256, 0, stream>>>(x, inv, Abf);
    gemm1_kernel<<<MAX_TILES * 32, 256, 0, stream>>>(Abf, winbf, actbuf, tiletab);
    gemm2_kernel<<<MAX_TILES * 16, 256, 0, stream>>>(actbuf, woutbf, ybA, ybB, tiletab);
    combine_kernel<<<N_TOK, 256, 0, stream>>>(ybA, ybB, inv, tok_gate, out);
}